// Round 11
// baseline (2547.584 us; speedup 1.0000x reference)
//
#include <hip/hip_runtime.h>

// ---------------------------------------------------------------------------
// IGCN link prediction, round 10.
// - Layer-2 collapsed to scalars (R4), bf16 S1 + MFMA GEMM (R6/R9),
//   bucket-binned edges (R8).
// - NEW: NO per-node sort. SpMM-1 aggregates per 128-node dst bucket in a
//   64KB LDS f32 tile (ds_add_f32, conflict-free lane->col (l, l+64) map),
//   fused bias/relu/3-way projection epilogue. Gate re-derived from the same
//   binned stream with 3-scalar LDS accumulators + tiny combine kernel.
//   Kills sort_k + rp2 + per-row loop tails; occupancy 16 waves x 2 blk/CU.
// ---------------------------------------------------------------------------

constexpr int BKT_SHIFT = 7;     // 128 nodes per bucket
constexpr int BKT_NODES = 128;

typedef __attribute__((ext_vector_type(8))) short bf16x8;
typedef __attribute__((ext_vector_type(4))) float f32x4;

__device__ __forceinline__ float wave_sum64(float x) {
#pragma unroll
    for (int o = 32; o > 0; o >>= 1) x += __shfl_xor(x, o, 64);
    return x;
}

__device__ __forceinline__ unsigned short f2bf(float f) {  // round-nearest-even
    unsigned int u = __float_as_uint(f);
    u += 0x7FFF + ((u >> 16) & 1);
    return (unsigned short)(u >> 16);
}

// ---------------- bucket binning (no per-node sort) ----------------

__global__ __launch_bounds__(256) void bhist_k(const int* __restrict__ eo,
                                               const int* __restrict__ es,
                                               int* __restrict__ bcnt,
                                               int E, int N, int nb) {
    __shared__ int lh[2048];
    for (int i = threadIdx.x; i < nb; i += 256) lh[i] = 0;
    __syncthreads();
    int total = 2 * E;
    for (int t = blockIdx.x * 256 + threadIdx.x; t < total; t += gridDim.x * 256) {
        int g = (t >= E) ? 1 : 0;
        int e = g ? t - E : t;
        int dst = (g ? es : eo)[e];
        atomicAdd(&lh[(g * N + dst) >> BKT_SHIFT], 1);
    }
    __syncthreads();
    for (int i = threadIdx.x; i < nb; i += 256) {
        int v = lh[i];
        if (v) atomicAdd(&bcnt[i], v);
    }
}

// scan up to 2048 bucket counts (2 elems/thread) -> bases + cursors
__global__ __launch_bounds__(1024) void bscan2_k(const int* __restrict__ bcnt,
                                                 int* __restrict__ bbase,
                                                 int* __restrict__ bcur,
                                                 int nb, int total) {
    __shared__ int sh[1024];
    int t = threadIdx.x;
    int i0 = 2 * t, i1 = 2 * t + 1;
    int v0 = (i0 < nb) ? bcnt[i0] : 0;
    int v1 = (i1 < nb) ? bcnt[i1] : 0;
    int p = v0 + v1;
    sh[t] = p;
    __syncthreads();
#pragma unroll
    for (int o = 1; o < 1024; o <<= 1) {
        int tv = (t >= o) ? sh[t - o] : 0;
        __syncthreads();
        sh[t] += tv;
        __syncthreads();
    }
    int excl = sh[t] - p;
    if (i0 < nb) { bbase[i0] = excl;      bcur[i0] = excl; }
    if (i1 < nb) { bbase[i1] = excl + v0; bcur[i1] = excl + v0; }
    if (t == 0) bbase[nb] = total;
}

// bin edges into 128-node buckets; per-block contiguous runs (L2-local).
// record: .x = (dst_local<<17) | src  (dl 7b, src 17b), .y = val bits
__global__ __launch_bounds__(256) void bin_k(const int* __restrict__ eo,
                                             const float* __restrict__ vo,
                                             const int* __restrict__ es,
                                             const float* __restrict__ vs,
                                             int* __restrict__ bcur,
                                             int2* __restrict__ binned,
                                             int E, int N, int nb, int chunk) {
    __shared__ int lcnt[2048];
    __shared__ int lbase[2048];
    int c0 = blockIdx.x * chunk;
    int c1 = min(c0 + chunk, 2 * E);
    for (int i = threadIdx.x; i < nb; i += 256) lcnt[i] = 0;
    __syncthreads();
    for (int t = c0 + threadIdx.x; t < c1; t += 256) {
        int g = (t >= E) ? 1 : 0;
        int e = g ? t - E : t;
        int dst = (g ? es : eo)[e];
        atomicAdd(&lcnt[(g * N + dst) >> BKT_SHIFT], 1);
    }
    __syncthreads();
    for (int i = threadIdx.x; i < nb; i += 256) {
        int v = lcnt[i];
        lbase[i] = v ? atomicAdd(&bcur[i], v) : 0;
        lcnt[i] = 0;  // reuse as local cursor
    }
    __syncthreads();
    for (int t = c0 + threadIdx.x; t < c1; t += 256) {
        int g = (t >= E) ? 1 : 0;
        int e = g ? t - E : t;
        const int* edges = g ? es : eo;
        int dst = edges[e];
        int dc = g * N + dst;
        int b = dc >> BKT_SHIFT;
        int pos = lbase[b] + atomicAdd(&lcnt[b], 1);
        int src = edges[E + e];
        float val = (g ? vs : vo)[e];
        binned[pos] = make_int2(((dc & (BKT_NODES - 1)) << 17) | src,
                                __float_as_int(val));
    }
}

// ---------------- precompute projections ----------------
__global__ void prep_k(const float* __restrict__ dec1_W, const float* __restrict__ dec1_b,
                       const float* __restrict__ dec2_W, const float* __restrict__ dec2_b,
                       const float* __restrict__ W_o2, const float* __restrict__ b_o2,
                       const float* __restrict__ W_s2, const float* __restrict__ b_s2,
                       const float* __restrict__ ag1, const float* __restrict__ ag2,
                       float* __restrict__ Mo, float* __restrict__ Ms,
                       float* __restrict__ beta, float* __restrict__ cc) {
    __shared__ float vsh[128];
    int t = threadIdx.x;  // 128 threads
    float s = 0.f;
    for (int j = 0; j < 64; ++j) s += dec1_W[t * 64 + j] * dec2_W[j];
    vsh[t] = s;
    __syncthreads();
    const float* vlo = vsh;
    const float* vhi = vsh + 64;
    float m0 = 0, m1 = 0, m2 = 0, n0 = 0, n1 = 0, n2 = 0;
    for (int k = 0; k < 64; ++k) {
        float wo = W_o2[t * 64 + k], wsv = W_s2[t * 64 + k];
        m0 += wo * ag1[k];  m1 += wo * vlo[k];  m2 += wo * vhi[k];
        n0 += wsv * ag2[k]; n1 += wsv * vlo[k]; n2 += wsv * vhi[k];
    }
    Mo[0 * 128 + t] = m0; Mo[1 * 128 + t] = m1; Mo[2 * 128 + t] = m2;
    Ms[0 * 128 + t] = n0; Ms[1 * 128 + t] = n1; Ms[2 * 128 + t] = n2;
    if (t == 0) {
        float b0 = 0, b1 = 0, b2 = 0, s0 = 0, s1 = 0, s2 = 0, c0 = 0;
        for (int k = 0; k < 64; ++k) {
            b0 += b_o2[k] * ag1[k]; b1 += b_o2[k] * vlo[k]; b2 += b_o2[k] * vhi[k];
            s0 += b_s2[k] * ag2[k]; s1 += b_s2[k] * vlo[k]; s2 += b_s2[k] * vhi[k];
            c0 += dec1_b[k] * dec2_W[k];
        }
        beta[0] = b0; beta[1] = b1; beta[2] = b2;
        beta[4] = s0; beta[5] = s1; beta[6] = s2;
        *cc = c0 + dec2_b[0];
    }
}

// ---------------- bf16 MFMA GEMM: S[b][n,128](bf16) = X @ W[b] (R9) ----------
__global__ __launch_bounds__(256) void gemm_mfma_k(const float* __restrict__ X,
                                                   const float* __restrict__ W0,
                                                   const float* __restrict__ W1,
                                                   unsigned short* __restrict__ S0,
                                                   unsigned short* __restrict__ S1,
                                                   int nrows) {
    __shared__ unsigned short XL[128 * 128];  // 32 KB
    __shared__ unsigned short WT[128 * 128];  // 32 KB

    const float* W = blockIdx.y ? W1 : W0;
    unsigned short* S = blockIdx.y ? S1 : S0;

    const int tid = threadIdx.x;
    const int row0 = blockIdx.x * 128;
    const float4* X4 = (const float4*)X;

#pragma unroll
    for (int i = 0; i < 16; ++i) {
        int f = i * 256 + tid;
        int r = f >> 5, q = f & 31;
        int gr = row0 + r;
        if (gr >= nrows) gr = nrows - 1;
        float4 v = X4[(size_t)gr * 32 + q];
        unsigned int w0 = (unsigned int)f2bf(v.x) | ((unsigned int)f2bf(v.y) << 16);
        unsigned int w1 = (unsigned int)f2bf(v.z) | ((unsigned int)f2bf(v.w) << 16);
        int bp = (q >> 1) ^ (r & 15);
        unsigned int* p = (unsigned int*)&XL[r * 128 + bp * 8 + (q & 1) * 4];
        p[0] = w0;
        p[1] = w1;
    }
    {
        int c = tid >> 1;
        int kh = (tid & 1) * 64;
#pragma unroll 8
        for (int k2 = 0; k2 < 32; ++k2) {
            int k = kh + 2 * k2;
            unsigned int lo = f2bf(W[k * 128 + c]);
            unsigned int hi = f2bf(W[(k + 1) * 128 + c]);
            int bp = (k >> 3) ^ (c & 15);
            ((unsigned int*)&WT[c * 128 + bp * 8])[(k >> 1) & 3] = lo | (hi << 16);
        }
    }
    __syncthreads();

    const int w4 = (tid >> 6) * 32;
    const int lr = tid & 15;
    const int kg = (tid >> 4) & 3;

    bf16x8 a[2][4];
#pragma unroll
    for (int rt = 0; rt < 2; ++rt)
#pragma unroll
        for (int kt = 0; kt < 4; ++kt)
            a[rt][kt] = *(const bf16x8*)&XL[(w4 + rt * 16 + lr) * 128 +
                                            (((kt * 4 + kg) ^ lr) * 8)];

    f32x4 acc[2][8];
#pragma unroll
    for (int rt = 0; rt < 2; ++rt)
#pragma unroll
        for (int ct = 0; ct < 8; ++ct) acc[rt][ct] = (f32x4){0.f, 0.f, 0.f, 0.f};

#pragma unroll
    for (int ct = 0; ct < 8; ++ct) {
#pragma unroll
        for (int kt = 0; kt < 4; ++kt) {
            bf16x8 b = *(const bf16x8*)&WT[(ct * 16 + lr) * 128 +
                                           (((kt * 4 + kg) ^ lr) * 8)];
            acc[0][ct] = __builtin_amdgcn_mfma_f32_16x16x32_bf16(a[0][kt], b, acc[0][ct], 0, 0, 0);
            acc[1][ct] = __builtin_amdgcn_mfma_f32_16x16x32_bf16(a[1][kt], b, acc[1][ct], 0, 0, 0);
        }
    }

#pragma unroll
    for (int rt = 0; rt < 2; ++rt)
#pragma unroll
        for (int j = 0; j < 4; ++j) {
            int gr = row0 + w4 + rt * 16 + kg * 4 + j;
            if (gr < nrows) {
                size_t rb = (size_t)gr * 128 + lr;
#pragma unroll
                for (int ct = 0; ct < 8; ++ct)
                    S[rb + ct * 16] = f2bf(acc[rt][ct][j]);
            }
        }
}

// ------- SpMM-1 per 128-node bucket: LDS f32 accum + bias/relu/projection ----
// 1024 threads (16 waves), 64KB LDS. lane l owns cols (l, 64+l): ds_add_f32
// at stride 4B -> 2 lanes/bank (free). Records streamed, both graphs mixed.
__global__ __launch_bounds__(1024) void spmm_bucket_k(
    const int* __restrict__ bbase, const int2* __restrict__ binned,
    const unsigned short* __restrict__ B0, const unsigned short* __restrict__ B1,
    const float* __restrict__ bias_o, const float* __restrict__ bias_s,
    const float* __restrict__ Mo, const float* __restrict__ Ms,
    float4* __restrict__ To, float4* __restrict__ Ts, int N, int n2) {
    __shared__ float acc[BKT_NODES * 128];  // 64 KB

    const int tid = threadIdx.x;
    const int b = blockIdx.x;
    const int base = bbase[b];
    const int cnt = bbase[b + 1] - base;
    const int dc0 = b << BKT_SHIFT;

#pragma unroll
    for (int i = 0; i < 16; ++i) acc[i * 1024 + tid] = 0.f;
    __syncthreads();

    const int wave = tid >> 6;
    const int l = tid & 63;

    int per = (cnt + 15) >> 4;
    int e = base + wave * per;
    int e1 = min(e + per, base + cnt);

    for (; e + 3 < e1; e += 4) {
        int2 cc[4];
#pragma unroll
        for (int q = 0; q < 4; ++q) cc[q] = binned[e + q];
        float mv0[4], mv1[4];
        int dlv[4];
#pragma unroll
        for (int q = 0; q < 4; ++q) {
            int dl = (cc[q].x >> 17) & (BKT_NODES - 1);
            int src = cc[q].x & 0x1FFFF;
            const unsigned short* Sp = ((dc0 + dl) < N) ? B0 : B1;
            float v = __int_as_float(cc[q].y);
            mv0[q] = __uint_as_float((unsigned int)Sp[src * 128 + l] << 16) * v;
            mv1[q] = __uint_as_float((unsigned int)Sp[src * 128 + 64 + l] << 16) * v;
            dlv[q] = dl;
        }
#pragma unroll
        for (int q = 0; q < 4; ++q) {
            atomicAdd(&acc[dlv[q] * 128 + l], mv0[q]);
            atomicAdd(&acc[dlv[q] * 128 + 64 + l], mv1[q]);
        }
    }
    for (; e < e1; ++e) {
        int2 c = binned[e];
        int dl = (c.x >> 17) & (BKT_NODES - 1);
        int src = c.x & 0x1FFFF;
        const unsigned short* Sp = ((dc0 + dl) < N) ? B0 : B1;
        float v = __int_as_float(c.y);
        atomicAdd(&acc[dl * 128 + l],
                  __uint_as_float((unsigned int)Sp[src * 128 + l] << 16) * v);
        atomicAdd(&acc[dl * 128 + 64 + l],
                  __uint_as_float((unsigned int)Sp[src * 128 + 64 + l] << 16) * v);
    }
    __syncthreads();

    // epilogue: wave handles 8 nodes
#pragma unroll
    for (int j = 0; j < 8; ++j) {
        int dl = wave * 8 + j;
        int dc = dc0 + dl;
        if (dc >= n2) break;
        bool gs = dc >= N;
        int node = gs ? dc - N : dc;
        const float* bias = gs ? bias_s : bias_o;
        const float* M = gs ? Ms : Mo;
        float ax = fmaxf(acc[dl * 128 + l] + bias[l], 0.f);
        float ay = fmaxf(acc[dl * 128 + 64 + l] + bias[64 + l], 0.f);
        float d = wave_sum64(ax * M[l] + ay * M[64 + l]);
        float u = wave_sum64(ax * M[128 + l] + ay * M[192 + l]);
        float w = wave_sum64(ax * M[256 + l] + ay * M[320 + l]);
        if (l == 0) (gs ? Ts : To)[node] = make_float4(d, u, w, 0.f);
    }
}

// ------- layer-2 scalar SpMM per bucket: 3-scalar LDS accum -> G[dc] ---------
__global__ __launch_bounds__(256) void gate_bucket_k(
    const int* __restrict__ bbase, const int2* __restrict__ binned,
    const float4* __restrict__ To, const float4* __restrict__ Ts,
    const float* __restrict__ beta, float4* __restrict__ G, int N, int n2) {
    __shared__ float acc[BKT_NODES * 4];  // 2 KB
    int tid = threadIdx.x, b = blockIdx.x;
    int base = bbase[b], cnt = bbase[b + 1] - base;
    int dc0 = b << BKT_SHIFT;
    for (int i = tid; i < BKT_NODES * 4; i += 256) acc[i] = 0.f;
    __syncthreads();
    for (int k = base + tid; k < base + cnt; k += 256) {
        int2 c = binned[k];
        int dl = (c.x >> 17) & (BKT_NODES - 1);
        int src = c.x & 0x1FFFF;
        float v = __int_as_float(c.y);
        float4 t = (((dc0 + dl) < N) ? To : Ts)[src];
        atomicAdd(&acc[dl * 4 + 0], t.x * v);
        atomicAdd(&acc[dl * 4 + 1], t.y * v);
        atomicAdd(&acc[dl * 4 + 2], t.z * v);
    }
    __syncthreads();
    if (tid < BKT_NODES) {
        int dc = dc0 + tid;
        if (dc < n2) {
            int off = (dc < N) ? 0 : 4;
            G[dc] = make_float4(acc[tid * 4 + 0] + beta[off],
                                acc[tid * 4 + 1] + beta[off + 1],
                                acc[tid * 4 + 2] + beta[off + 2], 0.f);
        }
    }
}

// ------- combine per node: a = d1*u1 + d2*u2 ; b = d1*w1 + d2*w2 -------------
__global__ __launch_bounds__(256) void combine_k(const float4* __restrict__ G,
                                                 float* __restrict__ a,
                                                 float* __restrict__ b, int n) {
    int i = blockIdx.x * 256 + threadIdx.x;
    if (i >= n) return;
    float4 g1 = G[i];
    float4 g2 = G[n + i];
    a[i] = g1.x * g1.y + g2.x * g2.y;
    b[i] = g1.x * g1.z + g2.x * g2.z;
}

__global__ __launch_bounds__(256) void decode_k(const int* __restrict__ idx,
                                                const float* __restrict__ a,
                                                const float* __restrict__ b,
                                                const float* __restrict__ c,
                                                float* __restrict__ out, int P) {
    int i = blockIdx.x * 256 + threadIdx.x;
    if (i >= P) return;
    out[i] = a[idx[i]] + b[idx[P + i]] + *c;
}

// ---------------------------------------------------------------------------

extern "C" void kernel_launch(void* const* d_in, const int* in_sizes, int n_in,
                              void* d_out, int out_size, void* d_ws, size_t ws_size,
                              hipStream_t stream) {
    const float* x      = (const float*)d_in[0];
    const int*   o_edges= (const int*)d_in[1];
    const float* o_vals = (const float*)d_in[2];
    const int*   s_edges= (const int*)d_in[3];
    const float* s_vals = (const float*)d_in[4];
    const int*   idx    = (const int*)d_in[5];
    const float* W_o1   = (const float*)d_in[6];
    const float* b_o1   = (const float*)d_in[7];
    const float* W_o2   = (const float*)d_in[8];
    const float* b_o2   = (const float*)d_in[9];
    const float* W_s1   = (const float*)d_in[10];
    const float* b_s1   = (const float*)d_in[11];
    const float* W_s2   = (const float*)d_in[12];
    const float* b_s2   = (const float*)d_in[13];
    const float* ag1    = (const float*)d_in[14];
    const float* ag2    = (const float*)d_in[15];
    const float* dec1_W = (const float*)d_in[16];
    const float* dec1_b = (const float*)d_in[17];
    const float* dec2_W = (const float*)d_in[18];
    const float* dec2_b = (const float*)d_in[19];
    float* out = (float*)d_out;

    const int N = in_sizes[0] / 128;
    const int E = in_sizes[1] / 2;
    const int P = out_size;
    const int n2 = 2 * N;
    const int nb = (n2 + BKT_NODES - 1) / BKT_NODES;  // 1563 for N=100k

    const size_t NBH = (size_t)N * 128 * 2;  // [N,128] bf16 bytes

    char* ws = (char*)d_ws;
    size_t off = 0;
    auto alloc = [&](size_t bytes) {
        char* p = ws + off;
        off += (bytes + 255) & ~(size_t)255;
        return p;
    };

    unsigned short* B0 = (unsigned short*)alloc(NBH);  // S1o (bf16)
    unsigned short* B1 = (unsigned short*)alloc(NBH);  // S1s (bf16)
    float4* To = (float4*)alloc((size_t)N * 16);
    float4* Ts = (float4*)alloc((size_t)N * 16);
    float4* G  = (float4*)alloc((size_t)n2 * 16);
    float* av = (float*)alloc((size_t)P * 4);
    float* bv = (float*)alloc((size_t)P * 4);
    float* Mo = (float*)alloc(3 * 128 * 4);
    float* Ms = (float*)alloc(3 * 128 * 4);
    float* beta = (float*)alloc(32);
    float* cc = (float*)alloc(16);
    int* bcnt  = (int*)alloc((size_t)nb * 4);
    int* bbase = (int*)alloc((size_t)(nb + 1) * 4);
    int* bcur  = (int*)alloc((size_t)nb * 4);
    int2* binned = (int2*)alloc((size_t)2 * E * 8);

    // ---- bucket binning ----
    hipMemsetAsync(bcnt, 0, (size_t)nb * 4, stream);
    bhist_k<<<512, 256, 0, stream>>>(o_edges, s_edges, bcnt, E, N, nb);
    bscan2_k<<<1, 1024, 0, stream>>>(bcnt, bbase, bcur, nb, 2 * E);
    const int chunk = 8192;
    bin_k<<<(2 * E + chunk - 1) / chunk, 256, 0, stream>>>(
        o_edges, o_vals, s_edges, s_vals, bcur, binned, E, N, nb, chunk);

    // ---- projection precompute ----
    prep_k<<<1, 128, 0, stream>>>(dec1_W, dec1_b, dec2_W, dec2_b,
                                  W_o2, b_o2, W_s2, b_s2, ag1, ag2,
                                  Mo, Ms, beta, cc);

    // ---- layer 1 GEMMs (both branches, bf16 MFMA) ----
    dim3 ggrid((N + 127) / 128, 2);
    gemm_mfma_k<<<ggrid, 256, 0, stream>>>(x, W_o1, W_s1, B0, B1, N);

    // ---- layer-1 SpMM per bucket (both graphs in one launch) ----
    spmm_bucket_k<<<nb, 1024, 0, stream>>>(bbase, binned, B0, B1, b_o1, b_s1,
                                           Mo, Ms, To, Ts, N, n2);

    // ---- layer-2 scalar SpMM per bucket ----
    gate_bucket_k<<<nb, 256, 0, stream>>>(bbase, binned, To, Ts, beta, G, N, n2);

    combine_k<<<(N + 255) / 256, 256, 0, stream>>>(G, av, bv, N);

    decode_k<<<(P + 255) / 256, 256, 0, stream>>>(idx, av, bv, cc, out, P);
}

// Round 12
// 320.670 us; speedup vs baseline: 7.9446x; 7.9446x over previous
//
#include <hip/hip_runtime.h>

// ---------------------------------------------------------------------------
// IGCN link prediction, round 11 = R9 (best passing, 315us) + paired-row
// gather in seg_spmm (2 rows per wave-load: lanes 0-31 row e, 32-63 row e+1,
// 8B/lane) -> halves VMEM instruction count at same traffic.
// R10's LDS-atomic bucket SpMM reverted (16x regression: serialization).
// ---------------------------------------------------------------------------

constexpr int BKT_SHIFT = 8;     // 256 nodes per bucket
constexpr int BKT_NODES = 256;
constexpr int SORT_CAP  = 7168;  // records/bucket LDS capacity

typedef __attribute__((ext_vector_type(8))) short bf16x8;
typedef __attribute__((ext_vector_type(4))) float f32x4;

__device__ __forceinline__ float wave_sum64(float x) {
#pragma unroll
    for (int o = 32; o > 0; o >>= 1) x += __shfl_xor(x, o, 64);
    return x;
}

__device__ __forceinline__ unsigned short f2bf(float f) {  // round-nearest-even
    unsigned int u = __float_as_uint(f);
    u += 0x7FFF + ((u >> 16) & 1);
    return (unsigned short)(u >> 16);
}

// ---------------- two-level bucket CSR build (R8) ----------------

__global__ __launch_bounds__(256) void bhist_k(const int* __restrict__ eo,
                                               const int* __restrict__ es,
                                               int* __restrict__ bcnt,
                                               int E, int N, int nb) {
    __shared__ int lh[1024];
    for (int i = threadIdx.x; i < nb; i += 256) lh[i] = 0;
    __syncthreads();
    int total = 2 * E;
    for (int t = blockIdx.x * 256 + threadIdx.x; t < total; t += gridDim.x * 256) {
        int g = (t >= E) ? 1 : 0;
        int e = g ? t - E : t;
        int dst = (g ? es : eo)[e];
        atomicAdd(&lh[(g * N + dst) >> BKT_SHIFT], 1);
    }
    __syncthreads();
    for (int i = threadIdx.x; i < nb; i += 256) {
        int v = lh[i];
        if (v) atomicAdd(&bcnt[i], v);
    }
}

__global__ __launch_bounds__(1024) void bscan_k(const int* __restrict__ bcnt,
                                                int* __restrict__ bbase,
                                                int* __restrict__ bcur,
                                                int nb, int total) {
    __shared__ int sh[1024];
    int t = threadIdx.x;
    int v = (t < nb) ? bcnt[t] : 0;
    sh[t] = v;
    __syncthreads();
#pragma unroll
    for (int o = 1; o < 1024; o <<= 1) {
        int tv = (t >= o) ? sh[t - o] : 0;
        __syncthreads();
        sh[t] += tv;
        __syncthreads();
    }
    if (t < nb) {
        int b = sh[t] - v;
        bbase[t] = b;
        bcur[t] = b;
    }
    if (t == 0) bbase[nb] = total;
}

__global__ __launch_bounds__(256) void bin_k(const int* __restrict__ eo,
                                             const float* __restrict__ vo,
                                             const int* __restrict__ es,
                                             const float* __restrict__ vs,
                                             int* __restrict__ bcur,
                                             int2* __restrict__ binned,
                                             int E, int N, int nb, int chunk) {
    __shared__ int lcnt[1024];
    __shared__ int lbase[1024];
    int c0 = blockIdx.x * chunk;
    int c1 = min(c0 + chunk, 2 * E);
    for (int i = threadIdx.x; i < nb; i += 256) lcnt[i] = 0;
    __syncthreads();
    for (int t = c0 + threadIdx.x; t < c1; t += 256) {
        int g = (t >= E) ? 1 : 0;
        int e = g ? t - E : t;
        int dst = (g ? es : eo)[e];
        atomicAdd(&lcnt[(g * N + dst) >> BKT_SHIFT], 1);
    }
    __syncthreads();
    for (int i = threadIdx.x; i < nb; i += 256) {
        int v = lcnt[i];
        lbase[i] = v ? atomicAdd(&bcur[i], v) : 0;
        lcnt[i] = 0;  // reuse as local cursor
    }
    __syncthreads();
    for (int t = c0 + threadIdx.x; t < c1; t += 256) {
        int g = (t >= E) ? 1 : 0;
        int e = g ? t - E : t;
        const int* edges = g ? es : eo;
        int dst = edges[e];
        int dc = g * N + dst;
        int b = dc >> BKT_SHIFT;
        int pos = lbase[b] + atomicAdd(&lcnt[b], 1);
        int src = edges[E + e];
        float val = (g ? vs : vo)[e];
        binned[pos] = make_int2(((dc & (BKT_NODES - 1)) << 17) | src,
                                __float_as_int(val));
    }
}

__global__ __launch_bounds__(256) void sort_k(const int* __restrict__ bbase,
                                              const int2* __restrict__ binned,
                                              int2* __restrict__ csr,
                                              int* __restrict__ rp2,
                                              int n2, int total) {
    __shared__ int2 lrec[SORT_CAP];
    __shared__ int ldeg[BKT_NODES];
    __shared__ int lsc[BKT_NODES];
    int b = blockIdx.x;
    int base = bbase[b];
    int count = min(bbase[b + 1] - base, SORT_CAP);
    int tid = threadIdx.x;
    for (int k = tid; k < count; k += 256) lrec[k] = binned[base + k];
    ldeg[tid] = 0;
    __syncthreads();
    for (int k = tid; k < count; k += 256) atomicAdd(&ldeg[lrec[k].x >> 17], 1);
    __syncthreads();
    int v = ldeg[tid];
    lsc[tid] = v;
    __syncthreads();
#pragma unroll
    for (int o = 1; o < 256; o <<= 1) {
        int tv = (tid >= o) ? lsc[tid - o] : 0;
        __syncthreads();
        lsc[tid] += tv;
        __syncthreads();
    }
    int excl = lsc[tid] - v;
    int node = b * BKT_NODES + tid;
    if (node < n2) rp2[node] = base + excl;
    if (b == 0 && tid == 0) rp2[n2] = total;
    ldeg[tid] = excl;  // reuse as scatter cursor
    __syncthreads();
    for (int k = tid; k < count; k += 256) {
        int2 r = lrec[k];
        int dl = r.x >> 17;
        int p = atomicAdd(&ldeg[dl], 1);
        csr[base + p] = make_int2(r.x & 0x1FFFF, r.y);
    }
}

// ---------------- precompute projections ----------------
__global__ void prep_k(const float* __restrict__ dec1_W, const float* __restrict__ dec1_b,
                       const float* __restrict__ dec2_W, const float* __restrict__ dec2_b,
                       const float* __restrict__ W_o2, const float* __restrict__ b_o2,
                       const float* __restrict__ W_s2, const float* __restrict__ b_s2,
                       const float* __restrict__ ag1, const float* __restrict__ ag2,
                       float* __restrict__ Mo, float* __restrict__ Ms,
                       float* __restrict__ beta, float* __restrict__ cc) {
    __shared__ float vsh[128];
    int t = threadIdx.x;  // 128 threads
    float s = 0.f;
    for (int j = 0; j < 64; ++j) s += dec1_W[t * 64 + j] * dec2_W[j];
    vsh[t] = s;
    __syncthreads();
    const float* vlo = vsh;
    const float* vhi = vsh + 64;
    float m0 = 0, m1 = 0, m2 = 0, n0 = 0, n1 = 0, n2 = 0;
    for (int k = 0; k < 64; ++k) {
        float wo = W_o2[t * 64 + k], wsv = W_s2[t * 64 + k];
        m0 += wo * ag1[k];  m1 += wo * vlo[k];  m2 += wo * vhi[k];
        n0 += wsv * ag2[k]; n1 += wsv * vlo[k]; n2 += wsv * vhi[k];
    }
    Mo[0 * 128 + t] = m0; Mo[1 * 128 + t] = m1; Mo[2 * 128 + t] = m2;
    Ms[0 * 128 + t] = n0; Ms[1 * 128 + t] = n1; Ms[2 * 128 + t] = n2;
    if (t == 0) {
        float b0 = 0, b1 = 0, b2 = 0, s0 = 0, s1 = 0, s2 = 0, c0 = 0;
        for (int k = 0; k < 64; ++k) {
            b0 += b_o2[k] * ag1[k]; b1 += b_o2[k] * vlo[k]; b2 += b_o2[k] * vhi[k];
            s0 += b_s2[k] * ag2[k]; s1 += b_s2[k] * vlo[k]; s2 += b_s2[k] * vhi[k];
            c0 += dec1_b[k] * dec2_W[k];
        }
        beta[0] = b0; beta[1] = b1; beta[2] = b2;
        beta[4] = s0; beta[5] = s1; beta[6] = s2;
        *cc = c0 + dec2_b[0];
    }
}

// ---------------- bf16 MFMA GEMM: S[b][n,128](bf16) = X @ W[b] (R9) ----------
__global__ __launch_bounds__(256) void gemm_mfma_k(const float* __restrict__ X,
                                                   const float* __restrict__ W0,
                                                   const float* __restrict__ W1,
                                                   unsigned short* __restrict__ S0,
                                                   unsigned short* __restrict__ S1,
                                                   int nrows) {
    __shared__ unsigned short XL[128 * 128];  // 32 KB
    __shared__ unsigned short WT[128 * 128];  // 32 KB

    const float* W = blockIdx.y ? W1 : W0;
    unsigned short* S = blockIdx.y ? S1 : S0;

    const int tid = threadIdx.x;
    const int row0 = blockIdx.x * 128;
    const float4* X4 = (const float4*)X;

#pragma unroll
    for (int i = 0; i < 16; ++i) {
        int f = i * 256 + tid;
        int r = f >> 5, q = f & 31;
        int gr = row0 + r;
        if (gr >= nrows) gr = nrows - 1;
        float4 v = X4[(size_t)gr * 32 + q];
        unsigned int w0 = (unsigned int)f2bf(v.x) | ((unsigned int)f2bf(v.y) << 16);
        unsigned int w1 = (unsigned int)f2bf(v.z) | ((unsigned int)f2bf(v.w) << 16);
        int bp = (q >> 1) ^ (r & 15);
        unsigned int* p = (unsigned int*)&XL[r * 128 + bp * 8 + (q & 1) * 4];
        p[0] = w0;
        p[1] = w1;
    }
    {
        int c = tid >> 1;
        int kh = (tid & 1) * 64;
#pragma unroll 8
        for (int k2 = 0; k2 < 32; ++k2) {
            int k = kh + 2 * k2;
            unsigned int lo = f2bf(W[k * 128 + c]);
            unsigned int hi = f2bf(W[(k + 1) * 128 + c]);
            int bp = (k >> 3) ^ (c & 15);
            ((unsigned int*)&WT[c * 128 + bp * 8])[(k >> 1) & 3] = lo | (hi << 16);
        }
    }
    __syncthreads();

    const int w4 = (tid >> 6) * 32;
    const int lr = tid & 15;
    const int kg = (tid >> 4) & 3;

    bf16x8 a[2][4];
#pragma unroll
    for (int rt = 0; rt < 2; ++rt)
#pragma unroll
        for (int kt = 0; kt < 4; ++kt)
            a[rt][kt] = *(const bf16x8*)&XL[(w4 + rt * 16 + lr) * 128 +
                                            (((kt * 4 + kg) ^ lr) * 8)];

    f32x4 acc[2][8];
#pragma unroll
    for (int rt = 0; rt < 2; ++rt)
#pragma unroll
        for (int ct = 0; ct < 8; ++ct) acc[rt][ct] = (f32x4){0.f, 0.f, 0.f, 0.f};

#pragma unroll
    for (int ct = 0; ct < 8; ++ct) {
#pragma unroll
        for (int kt = 0; kt < 4; ++kt) {
            bf16x8 b = *(const bf16x8*)&WT[(ct * 16 + lr) * 128 +
                                           (((kt * 4 + kg) ^ lr) * 8)];
            acc[0][ct] = __builtin_amdgcn_mfma_f32_16x16x32_bf16(a[0][kt], b, acc[0][ct], 0, 0, 0);
            acc[1][ct] = __builtin_amdgcn_mfma_f32_16x16x32_bf16(a[1][kt], b, acc[1][ct], 0, 0, 0);
        }
    }

#pragma unroll
    for (int rt = 0; rt < 2; ++rt)
#pragma unroll
        for (int j = 0; j < 4; ++j) {
            int gr = row0 + w4 + rt * 16 + kg * 4 + j;
            if (gr < nrows) {
                size_t rb = (size_t)gr * 128 + lr;
#pragma unroll
                for (int ct = 0; ct < 8; ++ct)
                    S[rb + ct * 16] = f2bf(acc[rt][ct][j]);
            }
        }
}

// ------- layer-1 gather SpMM: paired-row (2 edges per wave-load, 8B/lane) ----
// lanes 0-31 gather row src[e] (cols 4*lc..4*lc+3), lanes 32-63 row src[e+1].
// After the loop, shfl_xor(32) folds halves; each col appears twice in the
// wave -> projection reduces scaled by 0.5.
__global__ __launch_bounds__(256) void seg_spmm_fused2_k(
    const int* __restrict__ rp2, const int2* __restrict__ csr,
    const unsigned short* __restrict__ So, const unsigned short* __restrict__ Ss,
    const float* __restrict__ bias_o, const float* __restrict__ bias_s,
    const float* __restrict__ Mo, const float* __restrict__ Ms,
    float4* __restrict__ To, float4* __restrict__ Ts, int n) {
    const int* rp;
    const uint2* S2;
    const float* bias;
    const float* M;
    float4* T;
    if (blockIdx.y == 0) {
        rp = rp2;     S2 = (const uint2*)So; bias = bias_o; M = Mo; T = To;
    } else {
        rp = rp2 + n; S2 = (const uint2*)Ss; bias = bias_s; M = Ms; T = Ts;
    }
    int wid = (blockIdx.x * 256 + threadIdx.x) >> 6;
    int lane = threadIdx.x & 63;
    if (wid >= n) return;
    const int half = lane >> 5;
    const int lc = lane & 31;
    int e = rp[wid], end = rp[wid + 1];
    float a0 = 0.f, a1 = 0.f, a2 = 0.f, a3 = 0.f;

    // 4 pairs (8 edges) per iteration -> 4 independent 8B gathers in flight
    for (; e + 7 < end; e += 8) {
#pragma unroll
        for (int q = 0; q < 4; ++q) {
            int2 c0 = csr[e + 2 * q];
            int2 c1 = csr[e + 2 * q + 1];
            int src = half ? c1.x : c0.x;
            float v = __int_as_float(half ? c1.y : c0.y);
            uint2 m = S2[(size_t)src * 32 + lc];
            a0 += __uint_as_float(m.x << 16) * v;
            a1 += __uint_as_float(m.x & 0xFFFF0000u) * v;
            a2 += __uint_as_float(m.y << 16) * v;
            a3 += __uint_as_float(m.y & 0xFFFF0000u) * v;
        }
    }
    for (; e + 1 < end; e += 2) {
        int2 c0 = csr[e];
        int2 c1 = csr[e + 1];
        int src = half ? c1.x : c0.x;
        float v = __int_as_float(half ? c1.y : c0.y);
        uint2 m = S2[(size_t)src * 32 + lc];
        a0 += __uint_as_float(m.x << 16) * v;
        a1 += __uint_as_float(m.x & 0xFFFF0000u) * v;
        a2 += __uint_as_float(m.y << 16) * v;
        a3 += __uint_as_float(m.y & 0xFFFF0000u) * v;
    }
    if (e < end) {  // single leftover: upper half contributes 0
        int2 c0 = csr[e];
        int src = c0.x;
        float v = half ? 0.f : __int_as_float(c0.y);
        uint2 m = S2[(size_t)src * 32 + lc];
        a0 += __uint_as_float(m.x << 16) * v;
        a1 += __uint_as_float(m.x & 0xFFFF0000u) * v;
        a2 += __uint_as_float(m.y << 16) * v;
        a3 += __uint_as_float(m.y & 0xFFFF0000u) * v;
    }

    // fold the two halves: both now hold the full per-col sums
    a0 += __shfl_xor(a0, 32, 64);
    a1 += __shfl_xor(a1, 32, 64);
    a2 += __shfl_xor(a2, 32, 64);
    a3 += __shfl_xor(a3, 32, 64);

    // bias + relu (identical in both halves)
    float4 bb = ((const float4*)bias)[lc];
    a0 = fmaxf(a0 + bb.x, 0.f);
    a1 = fmaxf(a1 + bb.y, 0.f);
    a2 = fmaxf(a2 + bb.z, 0.f);
    a3 = fmaxf(a3 + bb.w, 0.f);

    // 3-way projection; each col counted twice across the wave -> *0.5
    float4 M0 = ((const float4*)(M + 0 * 128))[lc];
    float4 M1 = ((const float4*)(M + 1 * 128))[lc];
    float4 M2 = ((const float4*)(M + 2 * 128))[lc];
    float d = 0.5f * wave_sum64(a0 * M0.x + a1 * M0.y + a2 * M0.z + a3 * M0.w);
    float u = 0.5f * wave_sum64(a0 * M1.x + a1 * M1.y + a2 * M1.z + a3 * M1.w);
    float w = 0.5f * wave_sum64(a0 * M2.x + a1 * M2.y + a2 * M2.z + a3 * M2.w);
    if (lane == 0) T[wid] = make_float4(d, u, w, 0.f);
}

// ------- layer-2 scalar SpMM (both graphs) + gate + decode projections -------
__global__ __launch_bounds__(256) void gate_k(
    const int* __restrict__ rp2, const int2* __restrict__ csr,
    const float4* __restrict__ To, const float4* __restrict__ Ts,
    const float* __restrict__ beta,
    float* __restrict__ a, float* __restrict__ b, int n) {
    int i = blockIdx.x * 256 + threadIdx.x;
    if (i >= n) return;
    float d1 = 0.f, u1 = 0.f, w1 = 0.f;
    {
        int e = rp2[i], end = rp2[i + 1];
        for (; e + 3 < end; e += 4) {
            int2 c0 = csr[e], c1 = csr[e + 1], c2 = csr[e + 2], c3 = csr[e + 3];
            float4 t0 = To[c0.x];
            float4 t1 = To[c1.x];
            float4 t2 = To[c2.x];
            float4 t3 = To[c3.x];
            float v0 = __int_as_float(c0.y), v1 = __int_as_float(c1.y);
            float v2 = __int_as_float(c2.y), v3 = __int_as_float(c3.y);
            d1 += t0.x * v0 + t1.x * v1 + t2.x * v2 + t3.x * v3;
            u1 += t0.y * v0 + t1.y * v1 + t2.y * v2 + t3.y * v3;
            w1 += t0.z * v0 + t1.z * v1 + t2.z * v2 + t3.z * v3;
        }
        for (; e < end; ++e) {
            int2 c = csr[e];
            float4 t = To[c.x];
            float v = __int_as_float(c.y);
            d1 += t.x * v; u1 += t.y * v; w1 += t.z * v;
        }
    }
    float d2 = 0.f, u2 = 0.f, w2 = 0.f;
    {
        int e = rp2[n + i], end = rp2[n + i + 1];
        for (; e + 3 < end; e += 4) {
            int2 c0 = csr[e], c1 = csr[e + 1], c2 = csr[e + 2], c3 = csr[e + 3];
            float4 t0 = Ts[c0.x];
            float4 t1 = Ts[c1.x];
            float4 t2 = Ts[c2.x];
            float4 t3 = Ts[c3.x];
            float v0 = __int_as_float(c0.y), v1 = __int_as_float(c1.y);
            float v2 = __int_as_float(c2.y), v3 = __int_as_float(c3.y);
            d2 += t0.x * v0 + t1.x * v1 + t2.x * v2 + t3.x * v3;
            u2 += t0.y * v0 + t1.y * v1 + t2.y * v2 + t3.y * v3;
            w2 += t0.z * v0 + t1.z * v1 + t2.z * v2 + t3.z * v3;
        }
        for (; e < end; ++e) {
            int2 c = csr[e];
            float4 t = Ts[c.x];
            float v = __int_as_float(c.y);
            d2 += t.x * v; u2 += t.y * v; w2 += t.z * v;
        }
    }
    d1 += beta[0]; u1 += beta[1]; w1 += beta[2];
    d2 += beta[4]; u2 += beta[5]; w2 += beta[6];
    a[i] = d1 * u1 + d2 * u2;
    b[i] = d1 * w1 + d2 * w2;
}

__global__ __launch_bounds__(256) void decode_k(const int* __restrict__ idx,
                                                const float* __restrict__ a,
                                                const float* __restrict__ b,
                                                const float* __restrict__ c,
                                                float* __restrict__ out, int P) {
    int i = blockIdx.x * 256 + threadIdx.x;
    if (i >= P) return;
    out[i] = a[idx[i]] + b[idx[P + i]] + *c;
}

// ---------------------------------------------------------------------------

extern "C" void kernel_launch(void* const* d_in, const int* in_sizes, int n_in,
                              void* d_out, int out_size, void* d_ws, size_t ws_size,
                              hipStream_t stream) {
    const float* x      = (const float*)d_in[0];
    const int*   o_edges= (const int*)d_in[1];
    const float* o_vals = (const float*)d_in[2];
    const int*   s_edges= (const int*)d_in[3];
    const float* s_vals = (const float*)d_in[4];
    const int*   idx    = (const int*)d_in[5];
    const float* W_o1   = (const float*)d_in[6];
    const float* b_o1   = (const float*)d_in[7];
    const float* W_o2   = (const float*)d_in[8];
    const float* b_o2   = (const float*)d_in[9];
    const float* W_s1   = (const float*)d_in[10];
    const float* b_s1   = (const float*)d_in[11];
    const float* W_s2   = (const float*)d_in[12];
    const float* b_s2   = (const float*)d_in[13];
    const float* ag1    = (const float*)d_in[14];
    const float* ag2    = (const float*)d_in[15];
    const float* dec1_W = (const float*)d_in[16];
    const float* dec1_b = (const float*)d_in[17];
    const float* dec2_W = (const float*)d_in[18];
    const float* dec2_b = (const float*)d_in[19];
    float* out = (float*)d_out;

    const int N = in_sizes[0] / 128;
    const int E = in_sizes[1] / 2;
    const int P = out_size;
    const int n2 = 2 * N;
    const int nb = (n2 + BKT_NODES - 1) / BKT_NODES;  // 782 for N=100k

    const size_t NBH = (size_t)N * 128 * 2;  // [N,128] bf16 bytes

    char* ws = (char*)d_ws;
    size_t off = 0;
    auto alloc = [&](size_t bytes) {
        char* p = ws + off;
        off += (bytes + 255) & ~(size_t)255;
        return p;
    };

    unsigned short* B0 = (unsigned short*)alloc(NBH);  // S1o (bf16)
    unsigned short* B1 = (unsigned short*)alloc(NBH);  // S1s (bf16)
    float4* To = (float4*)alloc((size_t)N * 16);
    float4* Ts = (float4*)alloc((size_t)N * 16);
    float* av = (float*)alloc((size_t)P * 4);
    float* bv = (float*)alloc((size_t)P * 4);
    float* Mo = (float*)alloc(3 * 128 * 4);
    float* Ms = (float*)alloc(3 * 128 * 4);
    float* beta = (float*)alloc(32);
    float* cc = (float*)alloc(16);
    int* bcnt  = (int*)alloc((size_t)nb * 4);
    int* bbase = (int*)alloc((size_t)(nb + 1) * 4);
    int* bcur  = (int*)alloc((size_t)nb * 4);
    int* rp2   = (int*)alloc((size_t)(n2 + 1) * 4);
    int2* binned = (int2*)alloc((size_t)2 * E * 8);
    int2* csr    = (int2*)alloc((size_t)2 * E * 8);

    const int nblk = (N + 255) / 256;

    // ---- CSR build: two-level bucket sort ----
    hipMemsetAsync(bcnt, 0, (size_t)nb * 4, stream);
    bhist_k<<<512, 256, 0, stream>>>(o_edges, s_edges, bcnt, E, N, nb);
    bscan_k<<<1, 1024, 0, stream>>>(bcnt, bbase, bcur, nb, 2 * E);
    const int chunk = 8192;
    bin_k<<<(2 * E + chunk - 1) / chunk, 256, 0, stream>>>(
        o_edges, o_vals, s_edges, s_vals, bcur, binned, E, N, nb, chunk);
    sort_k<<<nb, 256, 0, stream>>>(bbase, binned, csr, rp2, n2, 2 * E);

    // ---- projection precompute ----
    prep_k<<<1, 128, 0, stream>>>(dec1_W, dec1_b, dec2_W, dec2_b,
                                  W_o2, b_o2, W_s2, b_s2, ag1, ag2,
                                  Mo, Ms, beta, cc);

    // ---- layer 1 GEMMs (both branches, bf16 MFMA) ----
    dim3 ggrid((N + 127) / 128, 2);
    gemm_mfma_k<<<ggrid, 256, 0, stream>>>(x, W_o1, W_s1, B0, B1, N);

    // ---- layer-1 SpMM + bias + relu + projection to 3 scalars (both) ----
    dim3 sgrid((N * 64 + 255) / 256, 2);
    seg_spmm_fused2_k<<<sgrid, 256, 0, stream>>>(rp2, csr, B0, B1, b_o1, b_s1,
                                                 Mo, Ms, To, Ts, N);

    // ---- layer-2 scalar SpMM + gate ----
    gate_k<<<nblk, 256, 0, stream>>>(rp2, csr, To, Ts, beta, av, bv, N);

    decode_k<<<(P + 255) / 256, 256, 0, stream>>>(idx, av, bv, cc, out, P);
}

// Round 13
// 313.494 us; speedup vs baseline: 8.1264x; 1.0229x over previous
//
#include <hip/hip_runtime.h>

// ---------------------------------------------------------------------------
// IGCN link prediction, round 12 = R9 (seg_spmm reverted to its 144us form;
// R11 paired-row gather regressed) + merged-branch MFMA GEMM: X staged in LDS
// ONCE, branch loop inside the block re-stages only W^T. GEMM HBM traffic
// 154MB -> ~103MB.
// ---------------------------------------------------------------------------

constexpr int BKT_SHIFT = 8;     // 256 nodes per bucket
constexpr int BKT_NODES = 256;
constexpr int SORT_CAP  = 7168;  // records/bucket LDS capacity

typedef __attribute__((ext_vector_type(8))) short bf16x8;
typedef __attribute__((ext_vector_type(4))) float f32x4;

__device__ __forceinline__ float wave_sum64(float x) {
#pragma unroll
    for (int o = 32; o > 0; o >>= 1) x += __shfl_xor(x, o, 64);
    return x;
}

__device__ __forceinline__ unsigned short f2bf(float f) {  // round-nearest-even
    unsigned int u = __float_as_uint(f);
    u += 0x7FFF + ((u >> 16) & 1);
    return (unsigned short)(u >> 16);
}

__device__ __forceinline__ float2 bf2f2(unsigned int u) {  // 2 bf16 -> 2 f32
    float2 r;
    r.x = __uint_as_float(u << 16);
    r.y = __uint_as_float(u & 0xFFFF0000u);
    return r;
}

// ---------------- two-level bucket CSR build (R8) ----------------

__global__ __launch_bounds__(256) void bhist_k(const int* __restrict__ eo,
                                               const int* __restrict__ es,
                                               int* __restrict__ bcnt,
                                               int E, int N, int nb) {
    __shared__ int lh[1024];
    for (int i = threadIdx.x; i < nb; i += 256) lh[i] = 0;
    __syncthreads();
    int total = 2 * E;
    for (int t = blockIdx.x * 256 + threadIdx.x; t < total; t += gridDim.x * 256) {
        int g = (t >= E) ? 1 : 0;
        int e = g ? t - E : t;
        int dst = (g ? es : eo)[e];
        atomicAdd(&lh[(g * N + dst) >> BKT_SHIFT], 1);
    }
    __syncthreads();
    for (int i = threadIdx.x; i < nb; i += 256) {
        int v = lh[i];
        if (v) atomicAdd(&bcnt[i], v);
    }
}

__global__ __launch_bounds__(1024) void bscan_k(const int* __restrict__ bcnt,
                                                int* __restrict__ bbase,
                                                int* __restrict__ bcur,
                                                int nb, int total) {
    __shared__ int sh[1024];
    int t = threadIdx.x;
    int v = (t < nb) ? bcnt[t] : 0;
    sh[t] = v;
    __syncthreads();
#pragma unroll
    for (int o = 1; o < 1024; o <<= 1) {
        int tv = (t >= o) ? sh[t - o] : 0;
        __syncthreads();
        sh[t] += tv;
        __syncthreads();
    }
    if (t < nb) {
        int b = sh[t] - v;
        bbase[t] = b;
        bcur[t] = b;
    }
    if (t == 0) bbase[nb] = total;
}

__global__ __launch_bounds__(256) void bin_k(const int* __restrict__ eo,
                                             const float* __restrict__ vo,
                                             const int* __restrict__ es,
                                             const float* __restrict__ vs,
                                             int* __restrict__ bcur,
                                             int2* __restrict__ binned,
                                             int E, int N, int nb, int chunk) {
    __shared__ int lcnt[1024];
    __shared__ int lbase[1024];
    int c0 = blockIdx.x * chunk;
    int c1 = min(c0 + chunk, 2 * E);
    for (int i = threadIdx.x; i < nb; i += 256) lcnt[i] = 0;
    __syncthreads();
    for (int t = c0 + threadIdx.x; t < c1; t += 256) {
        int g = (t >= E) ? 1 : 0;
        int e = g ? t - E : t;
        int dst = (g ? es : eo)[e];
        atomicAdd(&lcnt[(g * N + dst) >> BKT_SHIFT], 1);
    }
    __syncthreads();
    for (int i = threadIdx.x; i < nb; i += 256) {
        int v = lcnt[i];
        lbase[i] = v ? atomicAdd(&bcur[i], v) : 0;
        lcnt[i] = 0;  // reuse as local cursor
    }
    __syncthreads();
    for (int t = c0 + threadIdx.x; t < c1; t += 256) {
        int g = (t >= E) ? 1 : 0;
        int e = g ? t - E : t;
        const int* edges = g ? es : eo;
        int dst = edges[e];
        int dc = g * N + dst;
        int b = dc >> BKT_SHIFT;
        int pos = lbase[b] + atomicAdd(&lcnt[b], 1);
        int src = edges[E + e];
        float val = (g ? vs : vo)[e];
        binned[pos] = make_int2(((dc & (BKT_NODES - 1)) << 17) | src,
                                __float_as_int(val));
    }
}

__global__ __launch_bounds__(256) void sort_k(const int* __restrict__ bbase,
                                              const int2* __restrict__ binned,
                                              int2* __restrict__ csr,
                                              int* __restrict__ rp2,
                                              int n2, int total) {
    __shared__ int2 lrec[SORT_CAP];
    __shared__ int ldeg[BKT_NODES];
    __shared__ int lsc[BKT_NODES];
    int b = blockIdx.x;
    int base = bbase[b];
    int count = min(bbase[b + 1] - base, SORT_CAP);
    int tid = threadIdx.x;
    for (int k = tid; k < count; k += 256) lrec[k] = binned[base + k];
    ldeg[tid] = 0;
    __syncthreads();
    for (int k = tid; k < count; k += 256) atomicAdd(&ldeg[lrec[k].x >> 17], 1);
    __syncthreads();
    int v = ldeg[tid];
    lsc[tid] = v;
    __syncthreads();
#pragma unroll
    for (int o = 1; o < 256; o <<= 1) {
        int tv = (tid >= o) ? lsc[tid - o] : 0;
        __syncthreads();
        lsc[tid] += tv;
        __syncthreads();
    }
    int excl = lsc[tid] - v;
    int node = b * BKT_NODES + tid;
    if (node < n2) rp2[node] = base + excl;
    if (b == 0 && tid == 0) rp2[n2] = total;
    ldeg[tid] = excl;  // reuse as scatter cursor
    __syncthreads();
    for (int k = tid; k < count; k += 256) {
        int2 r = lrec[k];
        int dl = r.x >> 17;
        int p = atomicAdd(&ldeg[dl], 1);
        csr[base + p] = make_int2(r.x & 0x1FFFF, r.y);
    }
}

// ---------------- precompute projections ----------------
__global__ void prep_k(const float* __restrict__ dec1_W, const float* __restrict__ dec1_b,
                       const float* __restrict__ dec2_W, const float* __restrict__ dec2_b,
                       const float* __restrict__ W_o2, const float* __restrict__ b_o2,
                       const float* __restrict__ W_s2, const float* __restrict__ b_s2,
                       const float* __restrict__ ag1, const float* __restrict__ ag2,
                       float* __restrict__ Mo, float* __restrict__ Ms,
                       float* __restrict__ beta, float* __restrict__ cc) {
    __shared__ float vsh[128];
    int t = threadIdx.x;  // 128 threads
    float s = 0.f;
    for (int j = 0; j < 64; ++j) s += dec1_W[t * 64 + j] * dec2_W[j];
    vsh[t] = s;
    __syncthreads();
    const float* vlo = vsh;
    const float* vhi = vsh + 64;
    float m0 = 0, m1 = 0, m2 = 0, n0 = 0, n1 = 0, n2 = 0;
    for (int k = 0; k < 64; ++k) {
        float wo = W_o2[t * 64 + k], wsv = W_s2[t * 64 + k];
        m0 += wo * ag1[k];  m1 += wo * vlo[k];  m2 += wo * vhi[k];
        n0 += wsv * ag2[k]; n1 += wsv * vlo[k]; n2 += wsv * vhi[k];
    }
    Mo[0 * 128 + t] = m0; Mo[1 * 128 + t] = m1; Mo[2 * 128 + t] = m2;
    Ms[0 * 128 + t] = n0; Ms[1 * 128 + t] = n1; Ms[2 * 128 + t] = n2;
    if (t == 0) {
        float b0 = 0, b1 = 0, b2 = 0, s0 = 0, s1 = 0, s2 = 0, c0 = 0;
        for (int k = 0; k < 64; ++k) {
            b0 += b_o2[k] * ag1[k]; b1 += b_o2[k] * vlo[k]; b2 += b_o2[k] * vhi[k];
            s0 += b_s2[k] * ag2[k]; s1 += b_s2[k] * vlo[k]; s2 += b_s2[k] * vhi[k];
            c0 += dec1_b[k] * dec2_W[k];
        }
        beta[0] = b0; beta[1] = b1; beta[2] = b2;
        beta[4] = s0; beta[5] = s1; beta[6] = s2;
        *cc = c0 + dec2_b[0];
    }
}

// ------- merged-branch bf16 MFMA GEMM: S0,S1 = X @ {W0,W1}, X staged once ----
// 128-row tile/block, full K=128. XL staged once (32KB); WT re-staged per
// branch (32KB, barrier-guarded). A-fragments held in registers across both.
__global__ __launch_bounds__(256) void gemm_mfma2_k(const float* __restrict__ X,
                                                    const float* __restrict__ W0,
                                                    const float* __restrict__ W1,
                                                    unsigned short* __restrict__ S0,
                                                    unsigned short* __restrict__ S1,
                                                    int nrows) {
    __shared__ unsigned short XL[128 * 128];  // 32 KB
    __shared__ unsigned short WT[128 * 128];  // 32 KB

    const int tid = threadIdx.x;
    const int row0 = blockIdx.x * 128;
    const float4* X4 = (const float4*)X;

    // stage X tile -> XL (bf16, swizzled 16B blocks)
#pragma unroll
    for (int i = 0; i < 16; ++i) {
        int f = i * 256 + tid;
        int r = f >> 5, q = f & 31;
        int gr = row0 + r;
        if (gr >= nrows) gr = nrows - 1;
        float4 v = X4[(size_t)gr * 32 + q];
        unsigned int w0 = (unsigned int)f2bf(v.x) | ((unsigned int)f2bf(v.y) << 16);
        unsigned int w1 = (unsigned int)f2bf(v.z) | ((unsigned int)f2bf(v.w) << 16);
        int bp = (q >> 1) ^ (r & 15);
        unsigned int* p = (unsigned int*)&XL[r * 128 + bp * 8 + (q & 1) * 4];
        p[0] = w0;
        p[1] = w1;
    }

    const int w4 = (tid >> 6) * 32;
    const int lr = tid & 15;
    const int kg = (tid >> 4) & 3;

    bf16x8 a[2][4];
    bool a_loaded = false;

    for (int br = 0; br < 2; ++br) {
        const float* W = br ? W1 : W0;
        unsigned short* S = br ? S1 : S0;
        if (br) __syncthreads();  // all waves done reading WT(0) before restage
        {
            int c = tid >> 1;
            int kh = (tid & 1) * 64;
#pragma unroll 8
            for (int k2 = 0; k2 < 32; ++k2) {
                int k = kh + 2 * k2;
                unsigned int lo = f2bf(W[k * 128 + c]);
                unsigned int hi = f2bf(W[(k + 1) * 128 + c]);
                int bp = (k >> 3) ^ (c & 15);
                ((unsigned int*)&WT[c * 128 + bp * 8])[(k >> 1) & 3] = lo | (hi << 16);
            }
        }
        __syncthreads();

        if (!a_loaded) {
            a_loaded = true;
#pragma unroll
            for (int rt = 0; rt < 2; ++rt)
#pragma unroll
                for (int kt = 0; kt < 4; ++kt)
                    a[rt][kt] = *(const bf16x8*)&XL[(w4 + rt * 16 + lr) * 128 +
                                                    (((kt * 4 + kg) ^ lr) * 8)];
        }

        f32x4 acc[2][8];
#pragma unroll
        for (int rt = 0; rt < 2; ++rt)
#pragma unroll
            for (int ct = 0; ct < 8; ++ct) acc[rt][ct] = (f32x4){0.f, 0.f, 0.f, 0.f};

#pragma unroll
        for (int ct = 0; ct < 8; ++ct) {
#pragma unroll
            for (int kt = 0; kt < 4; ++kt) {
                bf16x8 b = *(const bf16x8*)&WT[(ct * 16 + lr) * 128 +
                                               (((kt * 4 + kg) ^ lr) * 8)];
                acc[0][ct] = __builtin_amdgcn_mfma_f32_16x16x32_bf16(a[0][kt], b, acc[0][ct], 0, 0, 0);
                acc[1][ct] = __builtin_amdgcn_mfma_f32_16x16x32_bf16(a[1][kt], b, acc[1][ct], 0, 0, 0);
            }
        }

        // D: col = lane&15, row = (lane>>4)*4 + reg
#pragma unroll
        for (int rt = 0; rt < 2; ++rt)
#pragma unroll
            for (int j = 0; j < 4; ++j) {
                int gr = row0 + w4 + rt * 16 + kg * 4 + j;
                if (gr < nrows) {
                    size_t rb = (size_t)gr * 128 + lr;
#pragma unroll
                    for (int ct = 0; ct < 8; ++ct)
                        S[rb + ct * 16] = f2bf(acc[rt][ct][j]);
                }
            }
    }
}

// ------- layer-1 gather SpMM (bf16 rows, R9 form) + bias/relu/projection -----
__global__ __launch_bounds__(256) void seg_spmm_fused2_k(
    const int* __restrict__ rp2, const int2* __restrict__ csr,
    const unsigned short* __restrict__ So, const unsigned short* __restrict__ Ss,
    const float* __restrict__ bias_o, const float* __restrict__ bias_s,
    const float* __restrict__ Mo, const float* __restrict__ Ms,
    float4* __restrict__ To, float4* __restrict__ Ts, int n) {
    const int* rp;
    const unsigned int* S;
    const float* bias;
    const float* M;
    float4* T;
    if (blockIdx.y == 0) {
        rp = rp2;     S = (const unsigned int*)So; bias = bias_o; M = Mo; T = To;
    } else {
        rp = rp2 + n; S = (const unsigned int*)Ss; bias = bias_s; M = Ms; T = Ts;
    }
    int wid = (blockIdx.x * 256 + threadIdx.x) >> 6;
    int lane = threadIdx.x & 63;
    if (wid >= n) return;
    int e = rp[wid], end = rp[wid + 1];
    float ax = 0.f, ay = 0.f;
    for (; e + 7 < end; e += 8) {
        int2 c0 = csr[e],     c1 = csr[e + 1], c2 = csr[e + 2], c3 = csr[e + 3];
        int2 c4 = csr[e + 4], c5 = csr[e + 5], c6 = csr[e + 6], c7 = csr[e + 7];
        float2 m0 = bf2f2(S[c0.x * 64 + lane]);
        float2 m1 = bf2f2(S[c1.x * 64 + lane]);
        float2 m2 = bf2f2(S[c2.x * 64 + lane]);
        float2 m3 = bf2f2(S[c3.x * 64 + lane]);
        float2 m4 = bf2f2(S[c4.x * 64 + lane]);
        float2 m5 = bf2f2(S[c5.x * 64 + lane]);
        float2 m6 = bf2f2(S[c6.x * 64 + lane]);
        float2 m7 = bf2f2(S[c7.x * 64 + lane]);
        float v0 = __int_as_float(c0.y), v1 = __int_as_float(c1.y);
        float v2 = __int_as_float(c2.y), v3 = __int_as_float(c3.y);
        float v4 = __int_as_float(c4.y), v5 = __int_as_float(c5.y);
        float v6 = __int_as_float(c6.y), v7 = __int_as_float(c7.y);
        ax += m0.x * v0 + m1.x * v1 + m2.x * v2 + m3.x * v3;
        ay += m0.y * v0 + m1.y * v1 + m2.y * v2 + m3.y * v3;
        ax += m4.x * v4 + m5.x * v5 + m6.x * v6 + m7.x * v7;
        ay += m4.y * v4 + m5.y * v5 + m6.y * v6 + m7.y * v7;
    }
    for (; e + 3 < end; e += 4) {
        int2 c0 = csr[e], c1 = csr[e + 1], c2 = csr[e + 2], c3 = csr[e + 3];
        float2 m0 = bf2f2(S[c0.x * 64 + lane]);
        float2 m1 = bf2f2(S[c1.x * 64 + lane]);
        float2 m2 = bf2f2(S[c2.x * 64 + lane]);
        float2 m3 = bf2f2(S[c3.x * 64 + lane]);
        float v0 = __int_as_float(c0.y), v1 = __int_as_float(c1.y);
        float v2 = __int_as_float(c2.y), v3 = __int_as_float(c3.y);
        ax += m0.x * v0 + m1.x * v1 + m2.x * v2 + m3.x * v3;
        ay += m0.y * v0 + m1.y * v1 + m2.y * v2 + m3.y * v3;
    }
    for (; e < end; ++e) {
        int2 c = csr[e];
        float2 m = bf2f2(S[c.x * 64 + lane]);
        float v = __int_as_float(c.y);
        ax += m.x * v;
        ay += m.y * v;
    }
    float2 bb = ((const float2*)bias)[lane];
    ax = fmaxf(ax + bb.x, 0.f);
    ay = fmaxf(ay + bb.y, 0.f);
    float2 M0 = ((const float2*)(M + 0 * 128))[lane];
    float2 M1 = ((const float2*)(M + 1 * 128))[lane];
    float2 M2 = ((const float2*)(M + 2 * 128))[lane];
    float d = wave_sum64(ax * M0.x + ay * M0.y);
    float u = wave_sum64(ax * M1.x + ay * M1.y);
    float w = wave_sum64(ax * M2.x + ay * M2.y);
    if (lane == 0) T[wid] = make_float4(d, u, w, 0.f);
}

// ------- layer-2 scalar SpMM (both graphs) + gate + decode projections -------
__global__ __launch_bounds__(256) void gate_k(
    const int* __restrict__ rp2, const int2* __restrict__ csr,
    const float4* __restrict__ To, const float4* __restrict__ Ts,
    const float* __restrict__ beta,
    float* __restrict__ a, float* __restrict__ b, int n) {
    int i = blockIdx.x * 256 + threadIdx.x;
    if (i >= n) return;
    float d1 = 0.f, u1 = 0.f, w1 = 0.f;
    {
        int e = rp2[i], end = rp2[i + 1];
        for (; e + 3 < end; e += 4) {
            int2 c0 = csr[e], c1 = csr[e + 1], c2 = csr[e + 2], c3 = csr[e + 3];
            float4 t0 = To[c0.x];
            float4 t1 = To[c1.x];
            float4 t2 = To[c2.x];
            float4 t3 = To[c3.x];
            float v0 = __int_as_float(c0.y), v1 = __int_as_float(c1.y);
            float v2 = __int_as_float(c2.y), v3 = __int_as_float(c3.y);
            d1 += t0.x * v0 + t1.x * v1 + t2.x * v2 + t3.x * v3;
            u1 += t0.y * v0 + t1.y * v1 + t2.y * v2 + t3.y * v3;
            w1 += t0.z * v0 + t1.z * v1 + t2.z * v2 + t3.z * v3;
        }
        for (; e < end; ++e) {
            int2 c = csr[e];
            float4 t = To[c.x];
            float v = __int_as_float(c.y);
            d1 += t.x * v; u1 += t.y * v; w1 += t.z * v;
        }
    }
    float d2 = 0.f, u2 = 0.f, w2 = 0.f;
    {
        int e = rp2[n + i], end = rp2[n + i + 1];
        for (; e + 3 < end; e += 4) {
            int2 c0 = csr[e], c1 = csr[e + 1], c2 = csr[e + 2], c3 = csr[e + 3];
            float4 t0 = Ts[c0.x];
            float4 t1 = Ts[c1.x];
            float4 t2 = Ts[c2.x];
            float4 t3 = Ts[c3.x];
            float v0 = __int_as_float(c0.y), v1 = __int_as_float(c1.y);
            float v2 = __int_as_float(c2.y), v3 = __int_as_float(c3.y);
            d2 += t0.x * v0 + t1.x * v1 + t2.x * v2 + t3.x * v3;
            u2 += t0.y * v0 + t1.y * v1 + t2.y * v2 + t3.y * v3;
            w2 += t0.z * v0 + t1.z * v1 + t2.z * v2 + t3.z * v3;
        }
        for (; e < end; ++e) {
            int2 c = csr[e];
            float4 t = Ts[c.x];
            float v = __int_as_float(c.y);
            d2 += t.x * v; u2 += t.y * v; w2 += t.z * v;
        }
    }
    d1 += beta[0]; u1 += beta[1]; w1 += beta[2];
    d2 += beta[4]; u2 += beta[5]; w2 += beta[6];
    a[i] = d1 * u1 + d2 * u2;
    b[i] = d1 * w1 + d2 * w2;
}

__global__ __launch_bounds__(256) void decode_k(const int* __restrict__ idx,
                                                const float* __restrict__ a,
                                                const float* __restrict__ b,
                                                const float* __restrict__ c,
                                                float* __restrict__ out, int P) {
    int i = blockIdx.x * 256 + threadIdx.x;
    if (i >= P) return;
    out[i] = a[idx[i]] + b[idx[P + i]] + *c;
}

// ---------------------------------------------------------------------------

extern "C" void kernel_launch(void* const* d_in, const int* in_sizes, int n_in,
                              void* d_out, int out_size, void* d_ws, size_t ws_size,
                              hipStream_t stream) {
    const float* x      = (const float*)d_in[0];
    const int*   o_edges= (const int*)d_in[1];
    const float* o_vals = (const float*)d_in[2];
    const int*   s_edges= (const int*)d_in[3];
    const float* s_vals = (const float*)d_in[4];
    const int*   idx    = (const int*)d_in[5];
    const float* W_o1   = (const float*)d_in[6];
    const float* b_o1   = (const float*)d_in[7];
    const float* W_o2   = (const float*)d_in[8];
    const float* b_o2   = (const float*)d_in[9];
    const float* W_s1   = (const float*)d_in[10];
    const float* b_s1   = (const float*)d_in[11];
    const float* W_s2   = (const float*)d_in[12];
    const float* b_s2   = (const float*)d_in[13];
    const float* ag1    = (const float*)d_in[14];
    const float* ag2    = (const float*)d_in[15];
    const float* dec1_W = (const float*)d_in[16];
    const float* dec1_b = (const float*)d_in[17];
    const float* dec2_W = (const float*)d_in[18];
    const float* dec2_b = (const float*)d_in[19];
    float* out = (float*)d_out;

    const int N = in_sizes[0] / 128;
    const int E = in_sizes[1] / 2;
    const int P = out_size;
    const int n2 = 2 * N;
    const int nb = (n2 + BKT_NODES - 1) / BKT_NODES;  // 782 for N=100k

    const size_t NBH = (size_t)N * 128 * 2;  // [N,128] bf16 bytes

    char* ws = (char*)d_ws;
    size_t off = 0;
    auto alloc = [&](size_t bytes) {
        char* p = ws + off;
        off += (bytes + 255) & ~(size_t)255;
        return p;
    };

    unsigned short* B0 = (unsigned short*)alloc(NBH);  // S1o (bf16)
    unsigned short* B1 = (unsigned short*)alloc(NBH);  // S1s (bf16)
    float4* To = (float4*)alloc((size_t)N * 16);
    float4* Ts = (float4*)alloc((size_t)N * 16);
    float* av = (float*)alloc((size_t)P * 4);
    float* bv = (float*)alloc((size_t)P * 4);
    float* Mo = (float*)alloc(3 * 128 * 4);
    float* Ms = (float*)alloc(3 * 128 * 4);
    float* beta = (float*)alloc(32);
    float* cc = (float*)alloc(16);
    int* bcnt  = (int*)alloc((size_t)nb * 4);
    int* bbase = (int*)alloc((size_t)(nb + 1) * 4);
    int* bcur  = (int*)alloc((size_t)nb * 4);
    int* rp2   = (int*)alloc((size_t)(n2 + 1) * 4);
    int2* binned = (int2*)alloc((size_t)2 * E * 8);
    int2* csr    = (int2*)alloc((size_t)2 * E * 8);

    const int nblk = (N + 255) / 256;

    // ---- CSR build: two-level bucket sort ----
    hipMemsetAsync(bcnt, 0, (size_t)nb * 4, stream);
    bhist_k<<<512, 256, 0, stream>>>(o_edges, s_edges, bcnt, E, N, nb);
    bscan_k<<<1, 1024, 0, stream>>>(bcnt, bbase, bcur, nb, 2 * E);
    const int chunk = 8192;
    bin_k<<<(2 * E + chunk - 1) / chunk, 256, 0, stream>>>(
        o_edges, o_vals, s_edges, s_vals, bcur, binned, E, N, nb, chunk);
    sort_k<<<nb, 256, 0, stream>>>(bbase, binned, csr, rp2, n2, 2 * E);

    // ---- projection precompute ----
    prep_k<<<1, 128, 0, stream>>>(dec1_W, dec1_b, dec2_W, dec2_b,
                                  W_o2, b_o2, W_s2, b_s2, ag1, ag2,
                                  Mo, Ms, beta, cc);

    // ---- layer 1 GEMMs (both branches in one block, X staged once) ----
    gemm_mfma2_k<<<(N + 127) / 128, 256, 0, stream>>>(x, W_o1, W_s1, B0, B1, N);

    // ---- layer-1 SpMM + bias + relu + projection to 3 scalars (both) ----
    dim3 sgrid((N * 64 + 255) / 256, 2);
    seg_spmm_fused2_k<<<sgrid, 256, 0, stream>>>(rp2, csr, B0, B1, b_o1, b_s1,
                                                 Mo, Ms, To, Ts, N);

    // ---- layer-2 scalar SpMM + gate ----
    gate_k<<<nblk, 256, 0, stream>>>(rp2, csr, To, Ts, beta, av, bv, N);

    decode_k<<<(P + 255) / 256, 256, 0, stream>>>(idx, av, bv, cc, out, P);
}

// Round 14
// 293.994 us; speedup vs baseline: 8.6654x; 1.0663x over previous
//
#include <hip/hip_runtime.h>

// ---------------------------------------------------------------------------
// IGCN link prediction, round 13 = R12 + "fat kernel": the independent
// dispatches {bin, gemm(both branches), prep} run as ONE kernel partitioned
// by blockIdx.x (roles: [0,gblocks)=gemm, [gblocks,+binblocks)=bin, last=prep).
// bin is atomic/latency-bound, gemm is LDS/MFMA-bound -> co-residency hides
// each other's stalls; removes ~25-30us of stream serialization.
// No numeric change anywhere: absmax must remain exactly 0.03125.
// ---------------------------------------------------------------------------

constexpr int BKT_SHIFT = 8;     // 256 nodes per bucket
constexpr int BKT_NODES = 256;
constexpr int SORT_CAP  = 7168;  // records/bucket LDS capacity

typedef __attribute__((ext_vector_type(8))) short bf16x8;
typedef __attribute__((ext_vector_type(4))) float f32x4;

__device__ __forceinline__ float wave_sum64(float x) {
#pragma unroll
    for (int o = 32; o > 0; o >>= 1) x += __shfl_xor(x, o, 64);
    return x;
}

__device__ __forceinline__ unsigned short f2bf(float f) {  // round-nearest-even
    unsigned int u = __float_as_uint(f);
    u += 0x7FFF + ((u >> 16) & 1);
    return (unsigned short)(u >> 16);
}

__device__ __forceinline__ float2 bf2f2(unsigned int u) {  // 2 bf16 -> 2 f32
    float2 r;
    r.x = __uint_as_float(u << 16);
    r.y = __uint_as_float(u & 0xFFFF0000u);
    return r;
}

// ---------------- CSR bucket build: hist + scan (unchanged R8) ----------------

__global__ __launch_bounds__(256) void bhist_k(const int* __restrict__ eo,
                                               const int* __restrict__ es,
                                               int* __restrict__ bcnt,
                                               int E, int N, int nb) {
    __shared__ int lh[1024];
    for (int i = threadIdx.x; i < nb; i += 256) lh[i] = 0;
    __syncthreads();
    int total = 2 * E;
    for (int t = blockIdx.x * 256 + threadIdx.x; t < total; t += gridDim.x * 256) {
        int g = (t >= E) ? 1 : 0;
        int e = g ? t - E : t;
        int dst = (g ? es : eo)[e];
        atomicAdd(&lh[(g * N + dst) >> BKT_SHIFT], 1);
    }
    __syncthreads();
    for (int i = threadIdx.x; i < nb; i += 256) {
        int v = lh[i];
        if (v) atomicAdd(&bcnt[i], v);
    }
}

__global__ __launch_bounds__(1024) void bscan_k(const int* __restrict__ bcnt,
                                                int* __restrict__ bbase,
                                                int* __restrict__ bcur,
                                                int nb, int total) {
    __shared__ int sh[1024];
    int t = threadIdx.x;
    int v = (t < nb) ? bcnt[t] : 0;
    sh[t] = v;
    __syncthreads();
#pragma unroll
    for (int o = 1; o < 1024; o <<= 1) {
        int tv = (t >= o) ? sh[t - o] : 0;
        __syncthreads();
        sh[t] += tv;
        __syncthreads();
    }
    if (t < nb) {
        int b = sh[t] - v;
        bbase[t] = b;
        bcur[t] = b;
    }
    if (t == 0) bbase[nb] = total;
}

// ---------------- fat-kernel roles ----------------

// role: bin edges into coarse buckets (same math as R12 bin_k)
__device__ __forceinline__ void bin_role(unsigned char* smem, int bb,
                                         const int* __restrict__ eo,
                                         const float* __restrict__ vo,
                                         const int* __restrict__ es,
                                         const float* __restrict__ vs,
                                         int* __restrict__ bcur,
                                         int2* __restrict__ binned,
                                         int E, int N, int nb, int chunk) {
    int* lcnt = (int*)smem;           // 1024 ints
    int* lbase = lcnt + 1024;         // 1024 ints
    int c0 = bb * chunk;
    int c1 = min(c0 + chunk, 2 * E);
    for (int i = threadIdx.x; i < nb; i += 256) lcnt[i] = 0;
    __syncthreads();
    for (int t = c0 + threadIdx.x; t < c1; t += 256) {
        int g = (t >= E) ? 1 : 0;
        int e = g ? t - E : t;
        int dst = (g ? es : eo)[e];
        atomicAdd(&lcnt[(g * N + dst) >> BKT_SHIFT], 1);
    }
    __syncthreads();
    for (int i = threadIdx.x; i < nb; i += 256) {
        int v = lcnt[i];
        lbase[i] = v ? atomicAdd(&bcur[i], v) : 0;
        lcnt[i] = 0;  // reuse as local cursor
    }
    __syncthreads();
    for (int t = c0 + threadIdx.x; t < c1; t += 256) {
        int g = (t >= E) ? 1 : 0;
        int e = g ? t - E : t;
        const int* edges = g ? es : eo;
        int dst = edges[e];
        int dc = g * N + dst;
        int b = dc >> BKT_SHIFT;
        int pos = lbase[b] + atomicAdd(&lcnt[b], 1);
        int src = edges[E + e];
        float val = (g ? vs : vo)[e];
        binned[pos] = make_int2(((dc & (BKT_NODES - 1)) << 17) | src,
                                __float_as_int(val));
    }
}

// role: merged-branch MFMA GEMM tile (same math as R12 gemm_mfma2_k)
__device__ __forceinline__ void gemm_role(unsigned char* smem, int blk,
                                          const float* __restrict__ X,
                                          const float* __restrict__ W0,
                                          const float* __restrict__ W1,
                                          unsigned short* __restrict__ S0,
                                          unsigned short* __restrict__ S1,
                                          int nrows) {
    unsigned short* XL = (unsigned short*)smem;      // 32 KB
    unsigned short* WT = XL + 128 * 128;             // 32 KB

    const int tid = threadIdx.x;
    const int row0 = blk * 128;
    const float4* X4 = (const float4*)X;

#pragma unroll
    for (int i = 0; i < 16; ++i) {
        int f = i * 256 + tid;
        int r = f >> 5, q = f & 31;
        int gr = row0 + r;
        if (gr >= nrows) gr = nrows - 1;
        float4 v = X4[(size_t)gr * 32 + q];
        unsigned int w0 = (unsigned int)f2bf(v.x) | ((unsigned int)f2bf(v.y) << 16);
        unsigned int w1 = (unsigned int)f2bf(v.z) | ((unsigned int)f2bf(v.w) << 16);
        int bp = (q >> 1) ^ (r & 15);
        unsigned int* p = (unsigned int*)&XL[r * 128 + bp * 8 + (q & 1) * 4];
        p[0] = w0;
        p[1] = w1;
    }

    const int w4 = (tid >> 6) * 32;
    const int lr = tid & 15;
    const int kg = (tid >> 4) & 3;

    bf16x8 a[2][4];
    bool a_loaded = false;

    for (int br = 0; br < 2; ++br) {
        const float* W = br ? W1 : W0;
        unsigned short* S = br ? S1 : S0;
        if (br) __syncthreads();  // all waves done reading WT(0) before restage
        {
            int c = tid >> 1;
            int kh = (tid & 1) * 64;
#pragma unroll 8
            for (int k2 = 0; k2 < 32; ++k2) {
                int k = kh + 2 * k2;
                unsigned int lo = f2bf(W[k * 128 + c]);
                unsigned int hi = f2bf(W[(k + 1) * 128 + c]);
                int bp = (k >> 3) ^ (c & 15);
                ((unsigned int*)&WT[c * 128 + bp * 8])[(k >> 1) & 3] = lo | (hi << 16);
            }
        }
        __syncthreads();

        if (!a_loaded) {
            a_loaded = true;
#pragma unroll
            for (int rt = 0; rt < 2; ++rt)
#pragma unroll
                for (int kt = 0; kt < 4; ++kt)
                    a[rt][kt] = *(const bf16x8*)&XL[(w4 + rt * 16 + lr) * 128 +
                                                    (((kt * 4 + kg) ^ lr) * 8)];
        }

        f32x4 acc[2][8];
#pragma unroll
        for (int rt = 0; rt < 2; ++rt)
#pragma unroll
            for (int ct = 0; ct < 8; ++ct) acc[rt][ct] = (f32x4){0.f, 0.f, 0.f, 0.f};

#pragma unroll
        for (int ct = 0; ct < 8; ++ct) {
#pragma unroll
            for (int kt = 0; kt < 4; ++kt) {
                bf16x8 b = *(const bf16x8*)&WT[(ct * 16 + lr) * 128 +
                                               (((kt * 4 + kg) ^ lr) * 8)];
                acc[0][ct] = __builtin_amdgcn_mfma_f32_16x16x32_bf16(a[0][kt], b, acc[0][ct], 0, 0, 0);
                acc[1][ct] = __builtin_amdgcn_mfma_f32_16x16x32_bf16(a[1][kt], b, acc[1][ct], 0, 0, 0);
            }
        }

#pragma unroll
        for (int rt = 0; rt < 2; ++rt)
#pragma unroll
            for (int j = 0; j < 4; ++j) {
                int gr = row0 + w4 + rt * 16 + kg * 4 + j;
                if (gr < nrows) {
                    size_t rb = (size_t)gr * 128 + lr;
#pragma unroll
                    for (int ct = 0; ct < 8; ++ct)
                        S[rb + ct * 16] = f2bf(acc[rt][ct][j]);
                }
            }
    }
}

// role: projection precompute (same math as R12 prep_k; barriers un-divergent)
__device__ __forceinline__ void prep_role(unsigned char* smem,
                                          const float* __restrict__ dec1_W,
                                          const float* __restrict__ dec1_b,
                                          const float* __restrict__ dec2_W,
                                          const float* __restrict__ dec2_b,
                                          const float* __restrict__ W_o2,
                                          const float* __restrict__ b_o2,
                                          const float* __restrict__ W_s2,
                                          const float* __restrict__ b_s2,
                                          const float* __restrict__ ag1,
                                          const float* __restrict__ ag2,
                                          float* __restrict__ Mo,
                                          float* __restrict__ Ms,
                                          float* __restrict__ beta,
                                          float* __restrict__ cc) {
    float* vsh = (float*)smem;  // 128 floats
    int t = threadIdx.x;
    if (t < 128) {
        float s = 0.f;
        for (int j = 0; j < 64; ++j) s += dec1_W[t * 64 + j] * dec2_W[j];
        vsh[t] = s;
    }
    __syncthreads();
    if (t < 128) {
        const float* vlo = vsh;
        const float* vhi = vsh + 64;
        float m0 = 0, m1 = 0, m2 = 0, n0 = 0, n1 = 0, n2 = 0;
        for (int k = 0; k < 64; ++k) {
            float wo = W_o2[t * 64 + k], wsv = W_s2[t * 64 + k];
            m0 += wo * ag1[k];  m1 += wo * vlo[k];  m2 += wo * vhi[k];
            n0 += wsv * ag2[k]; n1 += wsv * vlo[k]; n2 += wsv * vhi[k];
        }
        Mo[0 * 128 + t] = m0; Mo[1 * 128 + t] = m1; Mo[2 * 128 + t] = m2;
        Ms[0 * 128 + t] = n0; Ms[1 * 128 + t] = n1; Ms[2 * 128 + t] = n2;
        if (t == 0) {
            float b0 = 0, b1 = 0, b2 = 0, s0 = 0, s1 = 0, s2 = 0, c0 = 0;
            for (int k = 0; k < 64; ++k) {
                b0 += b_o2[k] * ag1[k]; b1 += b_o2[k] * vlo[k]; b2 += b_o2[k] * vhi[k];
                s0 += b_s2[k] * ag2[k]; s1 += b_s2[k] * vlo[k]; s2 += b_s2[k] * vhi[k];
                c0 += dec1_b[k] * dec2_W[k];
            }
            beta[0] = b0; beta[1] = b1; beta[2] = b2;
            beta[4] = s0; beta[5] = s1; beta[6] = s2;
            *cc = c0 + dec2_b[0];
        }
    }
}

// fat kernel: gemm blocks | bin blocks | prep block
__global__ __launch_bounds__(256) void fused_k(
    // role split
    int gblocks, int binblocks,
    // gemm
    const float* __restrict__ X, const float* __restrict__ W0,
    const float* __restrict__ W1, unsigned short* __restrict__ S0,
    unsigned short* __restrict__ S1, int nrows,
    // bin
    const int* __restrict__ eo, const float* __restrict__ vo,
    const int* __restrict__ es, const float* __restrict__ vs,
    int* __restrict__ bcur, int2* __restrict__ binned,
    int E, int N, int nb, int chunk,
    // prep
    const float* __restrict__ dec1_W, const float* __restrict__ dec1_b,
    const float* __restrict__ dec2_W, const float* __restrict__ dec2_b,
    const float* __restrict__ W_o2, const float* __restrict__ b_o2,
    const float* __restrict__ W_s2, const float* __restrict__ b_s2,
    const float* __restrict__ ag1, const float* __restrict__ ag2,
    float* __restrict__ Mo, float* __restrict__ Ms,
    float* __restrict__ beta, float* __restrict__ cc) {
    __shared__ __align__(16) unsigned char smem[64 * 1024];
    int bid = blockIdx.x;
    if (bid < gblocks) {
        gemm_role(smem, bid, X, W0, W1, S0, S1, nrows);
    } else if (bid < gblocks + binblocks) {
        bin_role(smem, bid - gblocks, eo, vo, es, vs, bcur, binned, E, N, nb, chunk);
    } else {
        prep_role(smem, dec1_W, dec1_b, dec2_W, dec2_b, W_o2, b_o2, W_s2, b_s2,
                  ag1, ag2, Mo, Ms, beta, cc);
    }
}

// ---------------- per-bucket sort (unchanged R8) ----------------

__global__ __launch_bounds__(256) void sort_k(const int* __restrict__ bbase,
                                              const int2* __restrict__ binned,
                                              int2* __restrict__ csr,
                                              int* __restrict__ rp2,
                                              int n2, int total) {
    __shared__ int2 lrec[SORT_CAP];
    __shared__ int ldeg[BKT_NODES];
    __shared__ int lsc[BKT_NODES];
    int b = blockIdx.x;
    int base = bbase[b];
    int count = min(bbase[b + 1] - base, SORT_CAP);
    int tid = threadIdx.x;
    for (int k = tid; k < count; k += 256) lrec[k] = binned[base + k];
    ldeg[tid] = 0;
    __syncthreads();
    for (int k = tid; k < count; k += 256) atomicAdd(&ldeg[lrec[k].x >> 17], 1);
    __syncthreads();
    int v = ldeg[tid];
    lsc[tid] = v;
    __syncthreads();
#pragma unroll
    for (int o = 1; o < 256; o <<= 1) {
        int tv = (tid >= o) ? lsc[tid - o] : 0;
        __syncthreads();
        lsc[tid] += tv;
        __syncthreads();
    }
    int excl = lsc[tid] - v;
    int node = b * BKT_NODES + tid;
    if (node < n2) rp2[node] = base + excl;
    if (b == 0 && tid == 0) rp2[n2] = total;
    ldeg[tid] = excl;  // reuse as scatter cursor
    __syncthreads();
    for (int k = tid; k < count; k += 256) {
        int2 r = lrec[k];
        int dl = r.x >> 17;
        int p = atomicAdd(&ldeg[dl], 1);
        csr[base + p] = make_int2(r.x & 0x1FFFF, r.y);
    }
}

// ------- layer-1 gather SpMM (bf16 rows, R9 form) + bias/relu/projection -----
__global__ __launch_bounds__(256) void seg_spmm_fused2_k(
    const int* __restrict__ rp2, const int2* __restrict__ csr,
    const unsigned short* __restrict__ So, const unsigned short* __restrict__ Ss,
    const float* __restrict__ bias_o, const float* __restrict__ bias_s,
    const float* __restrict__ Mo, const float* __restrict__ Ms,
    float4* __restrict__ To, float4* __restrict__ Ts, int n) {
    const int* rp;
    const unsigned int* S;
    const float* bias;
    const float* M;
    float4* T;
    if (blockIdx.y == 0) {
        rp = rp2;     S = (const unsigned int*)So; bias = bias_o; M = Mo; T = To;
    } else {
        rp = rp2 + n; S = (const unsigned int*)Ss; bias = bias_s; M = Ms; T = Ts;
    }
    int wid = (blockIdx.x * 256 + threadIdx.x) >> 6;
    int lane = threadIdx.x & 63;
    if (wid >= n) return;
    int e = rp[wid], end = rp[wid + 1];
    float ax = 0.f, ay = 0.f;
    for (; e + 7 < end; e += 8) {
        int2 c0 = csr[e],     c1 = csr[e + 1], c2 = csr[e + 2], c3 = csr[e + 3];
        int2 c4 = csr[e + 4], c5 = csr[e + 5], c6 = csr[e + 6], c7 = csr[e + 7];
        float2 m0 = bf2f2(S[c0.x * 64 + lane]);
        float2 m1 = bf2f2(S[c1.x * 64 + lane]);
        float2 m2 = bf2f2(S[c2.x * 64 + lane]);
        float2 m3 = bf2f2(S[c3.x * 64 + lane]);
        float2 m4 = bf2f2(S[c4.x * 64 + lane]);
        float2 m5 = bf2f2(S[c5.x * 64 + lane]);
        float2 m6 = bf2f2(S[c6.x * 64 + lane]);
        float2 m7 = bf2f2(S[c7.x * 64 + lane]);
        float v0 = __int_as_float(c0.y), v1 = __int_as_float(c1.y);
        float v2 = __int_as_float(c2.y), v3 = __int_as_float(c3.y);
        float v4 = __int_as_float(c4.y), v5 = __int_as_float(c5.y);
        float v6 = __int_as_float(c6.y), v7 = __int_as_float(c7.y);
        ax += m0.x * v0 + m1.x * v1 + m2.x * v2 + m3.x * v3;
        ay += m0.y * v0 + m1.y * v1 + m2.y * v2 + m3.y * v3;
        ax += m4.x * v4 + m5.x * v5 + m6.x * v6 + m7.x * v7;
        ay += m4.y * v4 + m5.y * v5 + m6.y * v6 + m7.y * v7;
    }
    for (; e + 3 < end; e += 4) {
        int2 c0 = csr[e], c1 = csr[e + 1], c2 = csr[e + 2], c3 = csr[e + 3];
        float2 m0 = bf2f2(S[c0.x * 64 + lane]);
        float2 m1 = bf2f2(S[c1.x * 64 + lane]);
        float2 m2 = bf2f2(S[c2.x * 64 + lane]);
        float2 m3 = bf2f2(S[c3.x * 64 + lane]);
        float v0 = __int_as_float(c0.y), v1 = __int_as_float(c1.y);
        float v2 = __int_as_float(c2.y), v3 = __int_as_float(c3.y);
        ax += m0.x * v0 + m1.x * v1 + m2.x * v2 + m3.x * v3;
        ay += m0.y * v0 + m1.y * v1 + m2.y * v2 + m3.y * v3;
    }
    for (; e < end; ++e) {
        int2 c = csr[e];
        float2 m = bf2f2(S[c.x * 64 + lane]);
        float v = __int_as_float(c.y);
        ax += m.x * v;
        ay += m.y * v;
    }
    float2 bb = ((const float2*)bias)[lane];
    ax = fmaxf(ax + bb.x, 0.f);
    ay = fmaxf(ay + bb.y, 0.f);
    float2 M0 = ((const float2*)(M + 0 * 128))[lane];
    float2 M1 = ((const float2*)(M + 1 * 128))[lane];
    float2 M2 = ((const float2*)(M + 2 * 128))[lane];
    float d = wave_sum64(ax * M0.x + ay * M0.y);
    float u = wave_sum64(ax * M1.x + ay * M1.y);
    float w = wave_sum64(ax * M2.x + ay * M2.y);
    if (lane == 0) T[wid] = make_float4(d, u, w, 0.f);
}

// ------- layer-2 scalar SpMM (both graphs) + gate + decode projections -------
__global__ __launch_bounds__(256) void gate_k(
    const int* __restrict__ rp2, const int2* __restrict__ csr,
    const float4* __restrict__ To, const float4* __restrict__ Ts,
    const float* __restrict__ beta,
    float* __restrict__ a, float* __restrict__ b, int n) {
    int i = blockIdx.x * 256 + threadIdx.x;
    if (i >= n) return;
    float d1 = 0.f, u1 = 0.f, w1 = 0.f;
    {
        int e = rp2[i], end = rp2[i + 1];
        for (; e + 3 < end; e += 4) {
            int2 c0 = csr[e], c1 = csr[e + 1], c2 = csr[e + 2], c3 = csr[e + 3];
            float4 t0 = To[c0.x];
            float4 t1 = To[c1.x];
            float4 t2 = To[c2.x];
            float4 t3 = To[c3.x];
            float v0 = __int_as_float(c0.y), v1 = __int_as_float(c1.y);
            float v2 = __int_as_float(c2.y), v3 = __int_as_float(c3.y);
            d1 += t0.x * v0 + t1.x * v1 + t2.x * v2 + t3.x * v3;
            u1 += t0.y * v0 + t1.y * v1 + t2.y * v2 + t3.y * v3;
            w1 += t0.z * v0 + t1.z * v1 + t2.z * v2 + t3.z * v3;
        }
        for (; e < end; ++e) {
            int2 c = csr[e];
            float4 t = To[c.x];
            float v = __int_as_float(c.y);
            d1 += t.x * v; u1 += t.y * v; w1 += t.z * v;
        }
    }
    float d2 = 0.f, u2 = 0.f, w2 = 0.f;
    {
        int e = rp2[n + i], end = rp2[n + i + 1];
        for (; e + 3 < end; e += 4) {
            int2 c0 = csr[e], c1 = csr[e + 1], c2 = csr[e + 2], c3 = csr[e + 3];
            float4 t0 = Ts[c0.x];
            float4 t1 = Ts[c1.x];
            float4 t2 = Ts[c2.x];
            float4 t3 = Ts[c3.x];
            float v0 = __int_as_float(c0.y), v1 = __int_as_float(c1.y);
            float v2 = __int_as_float(c2.y), v3 = __int_as_float(c3.y);
            d2 += t0.x * v0 + t1.x * v1 + t2.x * v2 + t3.x * v3;
            u2 += t0.y * v0 + t1.y * v1 + t2.y * v2 + t3.y * v3;
            w2 += t0.z * v0 + t1.z * v1 + t2.z * v2 + t3.z * v3;
        }
        for (; e < end; ++e) {
            int2 c = csr[e];
            float4 t = Ts[c.x];
            float v = __int_as_float(c.y);
            d2 += t.x * v; u2 += t.y * v; w2 += t.z * v;
        }
    }
    d1 += beta[0]; u1 += beta[1]; w1 += beta[2];
    d2 += beta[4]; u2 += beta[5]; w2 += beta[6];
    a[i] = d1 * u1 + d2 * u2;
    b[i] = d1 * w1 + d2 * w2;
}

__global__ __launch_bounds__(256) void decode_k(const int* __restrict__ idx,
                                                const float* __restrict__ a,
                                                const float* __restrict__ b,
                                                const float* __restrict__ c,
                                                float* __restrict__ out, int P) {
    int i = blockIdx.x * 256 + threadIdx.x;
    if (i >= P) return;
    out[i] = a[idx[i]] + b[idx[P + i]] + *c;
}

// ---------------------------------------------------------------------------

extern "C" void kernel_launch(void* const* d_in, const int* in_sizes, int n_in,
                              void* d_out, int out_size, void* d_ws, size_t ws_size,
                              hipStream_t stream) {
    const float* x      = (const float*)d_in[0];
    const int*   o_edges= (const int*)d_in[1];
    const float* o_vals = (const float*)d_in[2];
    const int*   s_edges= (const int*)d_in[3];
    const float* s_vals = (const float*)d_in[4];
    const int*   idx    = (const int*)d_in[5];
    const float* W_o1   = (const float*)d_in[6];
    const float* b_o1   = (const float*)d_in[7];
    const float* W_o2   = (const float*)d_in[8];
    const float* b_o2   = (const float*)d_in[9];
    const float* W_s1   = (const float*)d_in[10];
    const float* b_s1   = (const float*)d_in[11];
    const float* W_s2   = (const float*)d_in[12];
    const float* b_s2   = (const float*)d_in[13];
    const float* ag1    = (const float*)d_in[14];
    const float* ag2    = (const float*)d_in[15];
    const float* dec1_W = (const float*)d_in[16];
    const float* dec1_b = (const float*)d_in[17];
    const float* dec2_W = (const float*)d_in[18];
    const float* dec2_b = (const float*)d_in[19];
    float* out = (float*)d_out;

    const int N = in_sizes[0] / 128;
    const int E = in_sizes[1] / 2;
    const int P = out_size;
    const int n2 = 2 * N;
    const int nb = (n2 + BKT_NODES - 1) / BKT_NODES;  // 782 for N=100k

    const size_t NBH = (size_t)N * 128 * 2;  // [N,128] bf16 bytes

    char* ws = (char*)d_ws;
    size_t off = 0;
    auto alloc = [&](size_t bytes) {
        char* p = ws + off;
        off += (bytes + 255) & ~(size_t)255;
        return p;
    };

    unsigned short* B0 = (unsigned short*)alloc(NBH);  // S1o (bf16)
    unsigned short* B1 = (unsigned short*)alloc(NBH);  // S1s (bf16)
    float4* To = (float4*)alloc((size_t)N * 16);
    float4* Ts = (float4*)alloc((size_t)N * 16);
    float* av = (float*)alloc((size_t)P * 4);
    float* bv = (float*)alloc((size_t)P * 4);
    float* Mo = (float*)alloc(3 * 128 * 4);
    float* Ms = (float*)alloc(3 * 128 * 4);
    float* beta = (float*)alloc(32);
    float* cc = (float*)alloc(16);
    int* bcnt  = (int*)alloc((size_t)nb * 4);
    int* bbase = (int*)alloc((size_t)(nb + 1) * 4);
    int* bcur  = (int*)alloc((size_t)nb * 4);
    int* rp2   = (int*)alloc((size_t)(n2 + 1) * 4);
    int2* binned = (int2*)alloc((size_t)2 * E * 8);
    int2* csr    = (int2*)alloc((size_t)2 * E * 8);

    const int nblk = (N + 255) / 256;

    // ---- bucket hist + scan ----
    hipMemsetAsync(bcnt, 0, (size_t)nb * 4, stream);
    bhist_k<<<512, 256, 0, stream>>>(o_edges, s_edges, bcnt, E, N, nb);
    bscan_k<<<1, 1024, 0, stream>>>(bcnt, bbase, bcur, nb, 2 * E);

    // ---- fat kernel: gemm (both branches) || bin || prep ----
    const int chunk = 8192;
    const int gblocks = (N + 127) / 128;
    const int binblocks = (2 * E + chunk - 1) / chunk;
    fused_k<<<gblocks + binblocks + 1, 256, 0, stream>>>(
        gblocks, binblocks,
        x, W_o1, W_s1, B0, B1, N,
        o_edges, o_vals, s_edges, s_vals, bcur, binned, E, N, nb, chunk,
        dec1_W, dec1_b, dec2_W, dec2_b, W_o2, b_o2, W_s2, b_s2, ag1, ag2,
        Mo, Ms, beta, cc);

    // ---- per-bucket sort -> csr + rp2 ----
    sort_k<<<nb, 256, 0, stream>>>(bbase, binned, csr, rp2, n2, 2 * E);

    // ---- layer-1 SpMM + bias + relu + projection to 3 scalars (both) ----
    dim3 sgrid((N * 64 + 255) / 256, 2);
    seg_spmm_fused2_k<<<sgrid, 256, 0, stream>>>(rp2, csr, B0, B1, b_o1, b_s1,
                                                 Mo, Ms, To, Ts, N);

    // ---- layer-2 scalar SpMM + gate ----
    gate_k<<<nblk, 256, 0, stream>>>(rp2, csr, To, Ts, beta, av, bv, N);

    decode_k<<<(P + 255) / 256, 256, 0, stream>>>(idx, av, bv, cc, out, P);
}

// Round 15
// 293.433 us; speedup vs baseline: 8.6820x; 1.0019x over previous
//
#include <hip/hip_runtime.h>

// ---------------------------------------------------------------------------
// IGCN link prediction, round 13 = R12 + "fat kernel": the independent
// dispatches {bin, gemm(both branches), prep} run as ONE kernel partitioned
// by blockIdx.x (roles: [0,gblocks)=gemm, [gblocks,+binblocks)=bin, last=prep).
// bin is atomic/latency-bound, gemm is LDS/MFMA-bound -> co-residency hides
// each other's stalls; removes ~25-30us of stream serialization.
// No numeric change anywhere: absmax must remain exactly 0.03125.
// ---------------------------------------------------------------------------

constexpr int BKT_SHIFT = 8;     // 256 nodes per bucket
constexpr int BKT_NODES = 256;
constexpr int SORT_CAP  = 7168;  // records/bucket LDS capacity

typedef __attribute__((ext_vector_type(8))) short bf16x8;
typedef __attribute__((ext_vector_type(4))) float f32x4;

__device__ __forceinline__ float wave_sum64(float x) {
#pragma unroll
    for (int o = 32; o > 0; o >>= 1) x += __shfl_xor(x, o, 64);
    return x;
}

__device__ __forceinline__ unsigned short f2bf(float f) {  // round-nearest-even
    unsigned int u = __float_as_uint(f);
    u += 0x7FFF + ((u >> 16) & 1);
    return (unsigned short)(u >> 16);
}

__device__ __forceinline__ float2 bf2f2(unsigned int u) {  // 2 bf16 -> 2 f32
    float2 r;
    r.x = __uint_as_float(u << 16);
    r.y = __uint_as_float(u & 0xFFFF0000u);
    return r;
}

// ---------------- CSR bucket build: hist + scan (unchanged R8) ----------------

__global__ __launch_bounds__(256) void bhist_k(const int* __restrict__ eo,
                                               const int* __restrict__ es,
                                               int* __restrict__ bcnt,
                                               int E, int N, int nb) {
    __shared__ int lh[1024];
    for (int i = threadIdx.x; i < nb; i += 256) lh[i] = 0;
    __syncthreads();
    int total = 2 * E;
    for (int t = blockIdx.x * 256 + threadIdx.x; t < total; t += gridDim.x * 256) {
        int g = (t >= E) ? 1 : 0;
        int e = g ? t - E : t;
        int dst = (g ? es : eo)[e];
        atomicAdd(&lh[(g * N + dst) >> BKT_SHIFT], 1);
    }
    __syncthreads();
    for (int i = threadIdx.x; i < nb; i += 256) {
        int v = lh[i];
        if (v) atomicAdd(&bcnt[i], v);
    }
}

__global__ __launch_bounds__(1024) void bscan_k(const int* __restrict__ bcnt,
                                                int* __restrict__ bbase,
                                                int* __restrict__ bcur,
                                                int nb, int total) {
    __shared__ int sh[1024];
    int t = threadIdx.x;
    int v = (t < nb) ? bcnt[t] : 0;
    sh[t] = v;
    __syncthreads();
#pragma unroll
    for (int o = 1; o < 1024; o <<= 1) {
        int tv = (t >= o) ? sh[t - o] : 0;
        __syncthreads();
        sh[t] += tv;
        __syncthreads();
    }
    if (t < nb) {
        int b = sh[t] - v;
        bbase[t] = b;
        bcur[t] = b;
    }
    if (t == 0) bbase[nb] = total;
}

// ---------------- fat-kernel roles ----------------

// role: bin edges into coarse buckets (same math as R12 bin_k)
__device__ __forceinline__ void bin_role(unsigned char* smem, int bb,
                                         const int* __restrict__ eo,
                                         const float* __restrict__ vo,
                                         const int* __restrict__ es,
                                         const float* __restrict__ vs,
                                         int* __restrict__ bcur,
                                         int2* __restrict__ binned,
                                         int E, int N, int nb, int chunk) {
    int* lcnt = (int*)smem;           // 1024 ints
    int* lbase = lcnt + 1024;         // 1024 ints
    int c0 = bb * chunk;
    int c1 = min(c0 + chunk, 2 * E);
    for (int i = threadIdx.x; i < nb; i += 256) lcnt[i] = 0;
    __syncthreads();
    for (int t = c0 + threadIdx.x; t < c1; t += 256) {
        int g = (t >= E) ? 1 : 0;
        int e = g ? t - E : t;
        int dst = (g ? es : eo)[e];
        atomicAdd(&lcnt[(g * N + dst) >> BKT_SHIFT], 1);
    }
    __syncthreads();
    for (int i = threadIdx.x; i < nb; i += 256) {
        int v = lcnt[i];
        lbase[i] = v ? atomicAdd(&bcur[i], v) : 0;
        lcnt[i] = 0;  // reuse as local cursor
    }
    __syncthreads();
    for (int t = c0 + threadIdx.x; t < c1; t += 256) {
        int g = (t >= E) ? 1 : 0;
        int e = g ? t - E : t;
        const int* edges = g ? es : eo;
        int dst = edges[e];
        int dc = g * N + dst;
        int b = dc >> BKT_SHIFT;
        int pos = lbase[b] + atomicAdd(&lcnt[b], 1);
        int src = edges[E + e];
        float val = (g ? vs : vo)[e];
        binned[pos] = make_int2(((dc & (BKT_NODES - 1)) << 17) | src,
                                __float_as_int(val));
    }
}

// role: merged-branch MFMA GEMM tile (same math as R12 gemm_mfma2_k)
__device__ __forceinline__ void gemm_role(unsigned char* smem, int blk,
                                          const float* __restrict__ X,
                                          const float* __restrict__ W0,
                                          const float* __restrict__ W1,
                                          unsigned short* __restrict__ S0,
                                          unsigned short* __restrict__ S1,
                                          int nrows) {
    unsigned short* XL = (unsigned short*)smem;      // 32 KB
    unsigned short* WT = XL + 128 * 128;             // 32 KB

    const int tid = threadIdx.x;
    const int row0 = blk * 128;
    const float4* X4 = (const float4*)X;

#pragma unroll
    for (int i = 0; i < 16; ++i) {
        int f = i * 256 + tid;
        int r = f >> 5, q = f & 31;
        int gr = row0 + r;
        if (gr >= nrows) gr = nrows - 1;
        float4 v = X4[(size_t)gr * 32 + q];
        unsigned int w0 = (unsigned int)f2bf(v.x) | ((unsigned int)f2bf(v.y) << 16);
        unsigned int w1 = (unsigned int)f2bf(v.z) | ((unsigned int)f2bf(v.w) << 16);
        int bp = (q >> 1) ^ (r & 15);
        unsigned int* p = (unsigned int*)&XL[r * 128 + bp * 8 + (q & 1) * 4];
        p[0] = w0;
        p[1] = w1;
    }

    const int w4 = (tid >> 6) * 32;
    const int lr = tid & 15;
    const int kg = (tid >> 4) & 3;

    bf16x8 a[2][4];
    bool a_loaded = false;

    for (int br = 0; br < 2; ++br) {
        const float* W = br ? W1 : W0;
        unsigned short* S = br ? S1 : S0;
        if (br) __syncthreads();  // all waves done reading WT(0) before restage
        {
            int c = tid >> 1;
            int kh = (tid & 1) * 64;
#pragma unroll 8
            for (int k2 = 0; k2 < 32; ++k2) {
                int k = kh + 2 * k2;
                unsigned int lo = f2bf(W[k * 128 + c]);
                unsigned int hi = f2bf(W[(k + 1) * 128 + c]);
                int bp = (k >> 3) ^ (c & 15);
                ((unsigned int*)&WT[c * 128 + bp * 8])[(k >> 1) & 3] = lo | (hi << 16);
            }
        }
        __syncthreads();

        if (!a_loaded) {
            a_loaded = true;
#pragma unroll
            for (int rt = 0; rt < 2; ++rt)
#pragma unroll
                for (int kt = 0; kt < 4; ++kt)
                    a[rt][kt] = *(const bf16x8*)&XL[(w4 + rt * 16 + lr) * 128 +
                                                    (((kt * 4 + kg) ^ lr) * 8)];
        }

        f32x4 acc[2][8];
#pragma unroll
        for (int rt = 0; rt < 2; ++rt)
#pragma unroll
            for (int ct = 0; ct < 8; ++ct) acc[rt][ct] = (f32x4){0.f, 0.f, 0.f, 0.f};

#pragma unroll
        for (int ct = 0; ct < 8; ++ct) {
#pragma unroll
            for (int kt = 0; kt < 4; ++kt) {
                bf16x8 b = *(const bf16x8*)&WT[(ct * 16 + lr) * 128 +
                                               (((kt * 4 + kg) ^ lr) * 8)];
                acc[0][ct] = __builtin_amdgcn_mfma_f32_16x16x32_bf16(a[0][kt], b, acc[0][ct], 0, 0, 0);
                acc[1][ct] = __builtin_amdgcn_mfma_f32_16x16x32_bf16(a[1][kt], b, acc[1][ct], 0, 0, 0);
            }
        }

#pragma unroll
        for (int rt = 0; rt < 2; ++rt)
#pragma unroll
            for (int j = 0; j < 4; ++j) {
                int gr = row0 + w4 + rt * 16 + kg * 4 + j;
                if (gr < nrows) {
                    size_t rb = (size_t)gr * 128 + lr;
#pragma unroll
                    for (int ct = 0; ct < 8; ++ct)
                        S[rb + ct * 16] = f2bf(acc[rt][ct][j]);
                }
            }
    }
}

// role: projection precompute (same math as R12 prep_k; barriers un-divergent)
__device__ __forceinline__ void prep_role(unsigned char* smem,
                                          const float* __restrict__ dec1_W,
                                          const float* __restrict__ dec1_b,
                                          const float* __restrict__ dec2_W,
                                          const float* __restrict__ dec2_b,
                                          const float* __restrict__ W_o2,
                                          const float* __restrict__ b_o2,
                                          const float* __restrict__ W_s2,
                                          const float* __restrict__ b_s2,
                                          const float* __restrict__ ag1,
                                          const float* __restrict__ ag2,
                                          float* __restrict__ Mo,
                                          float* __restrict__ Ms,
                                          float* __restrict__ beta,
                                          float* __restrict__ cc) {
    float* vsh = (float*)smem;  // 128 floats
    int t = threadIdx.x;
    if (t < 128) {
        float s = 0.f;
        for (int j = 0; j < 64; ++j) s += dec1_W[t * 64 + j] * dec2_W[j];
        vsh[t] = s;
    }
    __syncthreads();
    if (t < 128) {
        const float* vlo = vsh;
        const float* vhi = vsh + 64;
        float m0 = 0, m1 = 0, m2 = 0, n0 = 0, n1 = 0, n2 = 0;
        for (int k = 0; k < 64; ++k) {
            float wo = W_o2[t * 64 + k], wsv = W_s2[t * 64 + k];
            m0 += wo * ag1[k];  m1 += wo * vlo[k];  m2 += wo * vhi[k];
            n0 += wsv * ag2[k]; n1 += wsv * vlo[k]; n2 += wsv * vhi[k];
        }
        Mo[0 * 128 + t] = m0; Mo[1 * 128 + t] = m1; Mo[2 * 128 + t] = m2;
        Ms[0 * 128 + t] = n0; Ms[1 * 128 + t] = n1; Ms[2 * 128 + t] = n2;
        if (t == 0) {
            float b0 = 0, b1 = 0, b2 = 0, s0 = 0, s1 = 0, s2 = 0, c0 = 0;
            for (int k = 0; k < 64; ++k) {
                b0 += b_o2[k] * ag1[k]; b1 += b_o2[k] * vlo[k]; b2 += b_o2[k] * vhi[k];
                s0 += b_s2[k] * ag2[k]; s1 += b_s2[k] * vlo[k]; s2 += b_s2[k] * vhi[k];
                c0 += dec1_b[k] * dec2_W[k];
            }
            beta[0] = b0; beta[1] = b1; beta[2] = b2;
            beta[4] = s0; beta[5] = s1; beta[6] = s2;
            *cc = c0 + dec2_b[0];
        }
    }
}

// fat kernel: gemm blocks | bin blocks | prep block
__global__ __launch_bounds__(256) void fused_k(
    // role split
    int gblocks, int binblocks,
    // gemm
    const float* __restrict__ X, const float* __restrict__ W0,
    const float* __restrict__ W1, unsigned short* __restrict__ S0,
    unsigned short* __restrict__ S1, int nrows,
    // bin
    const int* __restrict__ eo, const float* __restrict__ vo,
    const int* __restrict__ es, const float* __restrict__ vs,
    int* __restrict__ bcur, int2* __restrict__ binned,
    int E, int N, int nb, int chunk,
    // prep
    const float* __restrict__ dec1_W, const float* __restrict__ dec1_b,
    const float* __restrict__ dec2_W, const float* __restrict__ dec2_b,
    const float* __restrict__ W_o2, const float* __restrict__ b_o2,
    const float* __restrict__ W_s2, const float* __restrict__ b_s2,
    const float* __restrict__ ag1, const float* __restrict__ ag2,
    float* __restrict__ Mo, float* __restrict__ Ms,
    float* __restrict__ beta, float* __restrict__ cc) {
    __shared__ __align__(16) unsigned char smem[64 * 1024];
    int bid = blockIdx.x;
    if (bid < gblocks) {
        gemm_role(smem, bid, X, W0, W1, S0, S1, nrows);
    } else if (bid < gblocks + binblocks) {
        bin_role(smem, bid - gblocks, eo, vo, es, vs, bcur, binned, E, N, nb, chunk);
    } else {
        prep_role(smem, dec1_W, dec1_b, dec2_W, dec2_b, W_o2, b_o2, W_s2, b_s2,
                  ag1, ag2, Mo, Ms, beta, cc);
    }
}

// ---------------- per-bucket sort (unchanged R8) ----------------

__global__ __launch_bounds__(256) void sort_k(const int* __restrict__ bbase,
                                              const int2* __restrict__ binned,
                                              int2* __restrict__ csr,
                                              int* __restrict__ rp2,
                                              int n2, int total) {
    __shared__ int2 lrec[SORT_CAP];
    __shared__ int ldeg[BKT_NODES];
    __shared__ int lsc[BKT_NODES];
    int b = blockIdx.x;
    int base = bbase[b];
    int count = min(bbase[b + 1] - base, SORT_CAP);
    int tid = threadIdx.x;
    for (int k = tid; k < count; k += 256) lrec[k] = binned[base + k];
    ldeg[tid] = 0;
    __syncthreads();
    for (int k = tid; k < count; k += 256) atomicAdd(&ldeg[lrec[k].x >> 17], 1);
    __syncthreads();
    int v = ldeg[tid];
    lsc[tid] = v;
    __syncthreads();
#pragma unroll
    for (int o = 1; o < 256; o <<= 1) {
        int tv = (tid >= o) ? lsc[tid - o] : 0;
        __syncthreads();
        lsc[tid] += tv;
        __syncthreads();
    }
    int excl = lsc[tid] - v;
    int node = b * BKT_NODES + tid;
    if (node < n2) rp2[node] = base + excl;
    if (b == 0 && tid == 0) rp2[n2] = total;
    ldeg[tid] = excl;  // reuse as scatter cursor
    __syncthreads();
    for (int k = tid; k < count; k += 256) {
        int2 r = lrec[k];
        int dl = r.x >> 17;
        int p = atomicAdd(&ldeg[dl], 1);
        csr[base + p] = make_int2(r.x & 0x1FFFF, r.y);
    }
}

// ------- layer-1 gather SpMM (bf16 rows, R9 form) + bias/relu/projection -----
__global__ __launch_bounds__(256) void seg_spmm_fused2_k(
    const int* __restrict__ rp2, const int2* __restrict__ csr,
    const unsigned short* __restrict__ So, const unsigned short* __restrict__ Ss,
    const float* __restrict__ bias_o, const float* __restrict__ bias_s,
    const float* __restrict__ Mo, const float* __restrict__ Ms,
    float4* __restrict__ To, float4* __restrict__ Ts, int n) {
    const int* rp;
    const unsigned int* S;
    const float* bias;
    const float* M;
    float4* T;
    if (blockIdx.y == 0) {
        rp = rp2;     S = (const unsigned int*)So; bias = bias_o; M = Mo; T = To;
    } else {
        rp = rp2 + n; S = (const unsigned int*)Ss; bias = bias_s; M = Ms; T = Ts;
    }
    int wid = (blockIdx.x * 256 + threadIdx.x) >> 6;
    int lane = threadIdx.x & 63;
    if (wid >= n) return;
    int e = rp[wid], end = rp[wid + 1];
    float ax = 0.f, ay = 0.f;
    for (; e + 7 < end; e += 8) {
        int2 c0 = csr[e],     c1 = csr[e + 1], c2 = csr[e + 2], c3 = csr[e + 3];
        int2 c4 = csr[e + 4], c5 = csr[e + 5], c6 = csr[e + 6], c7 = csr[e + 7];
        float2 m0 = bf2f2(S[c0.x * 64 + lane]);
        float2 m1 = bf2f2(S[c1.x * 64 + lane]);
        float2 m2 = bf2f2(S[c2.x * 64 + lane]);
        float2 m3 = bf2f2(S[c3.x * 64 + lane]);
        float2 m4 = bf2f2(S[c4.x * 64 + lane]);
        float2 m5 = bf2f2(S[c5.x * 64 + lane]);
        float2 m6 = bf2f2(S[c6.x * 64 + lane]);
        float2 m7 = bf2f2(S[c7.x * 64 + lane]);
        float v0 = __int_as_float(c0.y), v1 = __int_as_float(c1.y);
        float v2 = __int_as_float(c2.y), v3 = __int_as_float(c3.y);
        float v4 = __int_as_float(c4.y), v5 = __int_as_float(c5.y);
        float v6 = __int_as_float(c6.y), v7 = __int_as_float(c7.y);
        ax += m0.x * v0 + m1.x * v1 + m2.x * v2 + m3.x * v3;
        ay += m0.y * v0 + m1.y * v1 + m2.y * v2 + m3.y * v3;
        ax += m4.x * v4 + m5.x * v5 + m6.x * v6 + m7.x * v7;
        ay += m4.y * v4 + m5.y * v5 + m6.y * v6 + m7.y * v7;
    }
    for (; e + 3 < end; e += 4) {
        int2 c0 = csr[e], c1 = csr[e + 1], c2 = csr[e + 2], c3 = csr[e + 3];
        float2 m0 = bf2f2(S[c0.x * 64 + lane]);
        float2 m1 = bf2f2(S[c1.x * 64 + lane]);
        float2 m2 = bf2f2(S[c2.x * 64 + lane]);
        float2 m3 = bf2f2(S[c3.x * 64 + lane]);
        float v0 = __int_as_float(c0.y), v1 = __int_as_float(c1.y);
        float v2 = __int_as_float(c2.y), v3 = __int_as_float(c3.y);
        ax += m0.x * v0 + m1.x * v1 + m2.x * v2 + m3.x * v3;
        ay += m0.y * v0 + m1.y * v1 + m2.y * v2 + m3.y * v3;
    }
    for (; e < end; ++e) {
        int2 c = csr[e];
        float2 m = bf2f2(S[c.x * 64 + lane]);
        float v = __int_as_float(c.y);
        ax += m.x * v;
        ay += m.y * v;
    }
    float2 bb = ((const float2*)bias)[lane];
    ax = fmaxf(ax + bb.x, 0.f);
    ay = fmaxf(ay + bb.y, 0.f);
    float2 M0 = ((const float2*)(M + 0 * 128))[lane];
    float2 M1 = ((const float2*)(M + 1 * 128))[lane];
    float2 M2 = ((const float2*)(M + 2 * 128))[lane];
    float d = wave_sum64(ax * M0.x + ay * M0.y);
    float u = wave_sum64(ax * M1.x + ay * M1.y);
    float w = wave_sum64(ax * M2.x + ay * M2.y);
    if (lane == 0) T[wid] = make_float4(d, u, w, 0.f);
}

// ------- layer-2 scalar SpMM (both graphs) + gate + decode projections -------
__global__ __launch_bounds__(256) void gate_k(
    const int* __restrict__ rp2, const int2* __restrict__ csr,
    const float4* __restrict__ To, const float4* __restrict__ Ts,
    const float* __restrict__ beta,
    float* __restrict__ a, float* __restrict__ b, int n) {
    int i = blockIdx.x * 256 + threadIdx.x;
    if (i >= n) return;
    float d1 = 0.f, u1 = 0.f, w1 = 0.f;
    {
        int e = rp2[i], end = rp2[i + 1];
        for (; e + 3 < end; e += 4) {
            int2 c0 = csr[e], c1 = csr[e + 1], c2 = csr[e + 2], c3 = csr[e + 3];
            float4 t0 = To[c0.x];
            float4 t1 = To[c1.x];
            float4 t2 = To[c2.x];
            float4 t3 = To[c3.x];
            float v0 = __int_as_float(c0.y), v1 = __int_as_float(c1.y);
            float v2 = __int_as_float(c2.y), v3 = __int_as_float(c3.y);
            d1 += t0.x * v0 + t1.x * v1 + t2.x * v2 + t3.x * v3;
            u1 += t0.y * v0 + t1.y * v1 + t2.y * v2 + t3.y * v3;
            w1 += t0.z * v0 + t1.z * v1 + t2.z * v2 + t3.z * v3;
        }
        for (; e < end; ++e) {
            int2 c = csr[e];
            float4 t = To[c.x];
            float v = __int_as_float(c.y);
            d1 += t.x * v; u1 += t.y * v; w1 += t.z * v;
        }
    }
    float d2 = 0.f, u2 = 0.f, w2 = 0.f;
    {
        int e = rp2[n + i], end = rp2[n + i + 1];
        for (; e + 3 < end; e += 4) {
            int2 c0 = csr[e], c1 = csr[e + 1], c2 = csr[e + 2], c3 = csr[e + 3];
            float4 t0 = Ts[c0.x];
            float4 t1 = Ts[c1.x];
            float4 t2 = Ts[c2.x];
            float4 t3 = Ts[c3.x];
            float v0 = __int_as_float(c0.y), v1 = __int_as_float(c1.y);
            float v2 = __int_as_float(c2.y), v3 = __int_as_float(c3.y);
            d2 += t0.x * v0 + t1.x * v1 + t2.x * v2 + t3.x * v3;
            u2 += t0.y * v0 + t1.y * v1 + t2.y * v2 + t3.y * v3;
            w2 += t0.z * v0 + t1.z * v1 + t2.z * v2 + t3.z * v3;
        }
        for (; e < end; ++e) {
            int2 c = csr[e];
            float4 t = Ts[c.x];
            float v = __int_as_float(c.y);
            d2 += t.x * v; u2 += t.y * v; w2 += t.z * v;
        }
    }
    d1 += beta[0]; u1 += beta[1]; w1 += beta[2];
    d2 += beta[4]; u2 += beta[5]; w2 += beta[6];
    a[i] = d1 * u1 + d2 * u2;
    b[i] = d1 * w1 + d2 * w2;
}

__global__ __launch_bounds__(256) void decode_k(const int* __restrict__ idx,
                                                const float* __restrict__ a,
                                                const float* __restrict__ b,
                                                const float* __restrict__ c,
                                                float* __restrict__ out, int P) {
    int i = blockIdx.x * 256 + threadIdx.x;
    if (i >= P) return;
    out[i] = a[idx[i]] + b[idx[P + i]] + *c;
}

// ---------------------------------------------------------------------------

extern "C" void kernel_launch(void* const* d_in, const int* in_sizes, int n_in,
                              void* d_out, int out_size, void* d_ws, size_t ws_size,
                              hipStream_t stream) {
    const float* x      = (const float*)d_in[0];
    const int*   o_edges= (const int*)d_in[1];
    const float* o_vals = (const float*)d_in[2];
    const int*   s_edges= (const int*)d_in[3];
    const float* s_vals = (const float*)d_in[4];
    const int*   idx    = (const int*)d_in[5];
    const float* W_o1   = (const float*)d_in[6];
    const float* b_o1   = (const float*)d_in[7];
    const float* W_o2   = (const float*)d_in[8];
    const float* b_o2   = (const float*)d_in[9];
    const float* W_s1   = (const float*)d_in[10];
    const float* b_s1   = (const float*)d_in[11];
    const float* W_s2   = (const float*)d_in[12];
    const float* b_s2   = (const float*)d_in[13];
    const float* ag1    = (const float*)d_in[14];
    const float* ag2    = (const float*)d_in[15];
    const float* dec1_W = (const float*)d_in[16];
    const float* dec1_b = (const float*)d_in[17];
    const float* dec2_W = (const float*)d_in[18];
    const float* dec2_b = (const float*)d_in[19];
    float* out = (float*)d_out;

    const int N = in_sizes[0] / 128;
    const int E = in_sizes[1] / 2;
    const int P = out_size;
    const int n2 = 2 * N;
    const int nb = (n2 + BKT_NODES - 1) / BKT_NODES;  // 782 for N=100k

    const size_t NBH = (size_t)N * 128 * 2;  // [N,128] bf16 bytes

    char* ws = (char*)d_ws;
    size_t off = 0;
    auto alloc = [&](size_t bytes) {
        char* p = ws + off;
        off += (bytes + 255) & ~(size_t)255;
        return p;
    };

    unsigned short* B0 = (unsigned short*)alloc(NBH);  // S1o (bf16)
    unsigned short* B1 = (unsigned short*)alloc(NBH);  // S1s (bf16)
    float4* To = (float4*)alloc((size_t)N * 16);
    float4* Ts = (float4*)alloc((size_t)N * 16);
    float* av = (float*)alloc((size_t)P * 4);
    float* bv = (float*)alloc((size_t)P * 4);
    float* Mo = (float*)alloc(3 * 128 * 4);
    float* Ms = (float*)alloc(3 * 128 * 4);
    float* beta = (float*)alloc(32);
    float* cc = (float*)alloc(16);
    int* bcnt  = (int*)alloc((size_t)nb * 4);
    int* bbase = (int*)alloc((size_t)(nb + 1) * 4);
    int* bcur  = (int*)alloc((size_t)nb * 4);
    int* rp2   = (int*)alloc((size_t)(n2 + 1) * 4);
    int2* binned = (int2*)alloc((size_t)2 * E * 8);
    int2* csr    = (int2*)alloc((size_t)2 * E * 8);

    const int nblk = (N + 255) / 256;

    // ---- bucket hist + scan ----
    hipMemsetAsync(bcnt, 0, (size_t)nb * 4, stream);
    bhist_k<<<512, 256, 0, stream>>>(o_edges, s_edges, bcnt, E, N, nb);
    bscan_k<<<1, 1024, 0, stream>>>(bcnt, bbase, bcur, nb, 2 * E);

    // ---- fat kernel: gemm (both branches) || bin || prep ----
    const int chunk = 8192;
    const int gblocks = (N + 127) / 128;
    const int binblocks = (2 * E + chunk - 1) / chunk;
    fused_k<<<gblocks + binblocks + 1, 256, 0, stream>>>(
        gblocks, binblocks,
        x, W_o1, W_s1, B0, B1, N,
        o_edges, o_vals, s_edges, s_vals, bcur, binned, E, N, nb, chunk,
        dec1_W, dec1_b, dec2_W, dec2_b, W_o2, b_o2, W_s2, b_s2, ag1, ag2,
        Mo, Ms, beta, cc);

    // ---- per-bucket sort -> csr + rp2 ----
    sort_k<<<nb, 256, 0, stream>>>(bbase, binned, csr, rp2, n2, 2 * E);

    // ---- layer-1 SpMM + bias + relu + projection to 3 scalars (both) ----
    dim3 sgrid((N * 64 + 255) / 256, 2);
    seg_spmm_fused2_k<<<sgrid, 256, 0, stream>>>(rp2, csr, B0, B1, b_o1, b_s1,
                                                 Mo, Ms, To, Ts, N);

    // ---- layer-2 scalar SpMM + gate ----
    gate_k<<<nblk, 256, 0, stream>>>(rp2, csr, To, Ts, beta, av, bv, N);

    decode_k<<<(P + 255) / 256, 256, 0, stream>>>(idx, av, bv, cc, out, P);
}